// Round 6
// baseline (258.584 us; speedup 1.0000x reference)
//
#include <hip/hip_runtime.h>

#define NB 32768

typedef _Float16 half8 __attribute__((ext_vector_type(8)));
typedef float floatx4 __attribute__((ext_vector_type(4)));
typedef float floatx2 __attribute__((ext_vector_type(2)));
typedef unsigned int uint4v __attribute__((ext_vector_type(4)));

#define MFMA16(a,b,c) __builtin_amdgcn_mfma_f32_16x16x32_f16(a,b,c,0,0,0)

// ---------- fast math ----------
__device__ __forceinline__ float rcp_f(float x){ return __builtin_amdgcn_rcpf(x); }
__device__ __forceinline__ float exp2_f(float x){ return __builtin_amdgcn_exp2f(x); }
__device__ __forceinline__ float tanh_f(float x){
  float e = exp2_f(x * 2.8853900817779268f);     // e^(2x)
  return (e - 1.0f) * rcp_f(e + 1.0f);
}
__device__ __forceinline__ float sigmoid_f(float x){
  return rcp_f(1.0f + exp2_f(-1.4426950408889634f * x));
}

// packed f32 math (VOP3P)
__device__ __forceinline__ floatx2 pk_mul2(floatx2 a, floatx2 b){
  floatx2 d; asm("v_pk_mul_f32 %0, %1, %2" : "=v"(d) : "v"(a), "v"(b)); return d;
}
__device__ __forceinline__ floatx2 pk_fma2(floatx2 a, floatx2 b, floatx2 c){
  floatx2 d; asm("v_pk_fma_f32 %0, %1, %2, %3" : "=v"(d) : "v"(a), "v"(b), "v"(c)); return d;
}

// DPP quad butterflies: xor1 = quad_perm[1,0,3,2]=0xB1, xor2 = [2,3,0,1]=0x4E
template<int CTRL>
__device__ __forceinline__ float dpp_qp(float x){
  return __builtin_bit_cast(float, __builtin_amdgcn_update_dpp(0, __builtin_bit_cast(int,x), CTRL, 0xF, 0xF, true));
}
__device__ __forceinline__ float qadd2(float x){
  x += dpp_qp<0xB1>(x);
  x += dpp_qp<0x4E>(x);
  return x;
}
__device__ __forceinline__ float qmax2(float x){
  x = fmaxf(x, dpp_qp<0xB1>(x));
  x = fmaxf(x, dpp_qp<0x4E>(x));
  return x;
}

// ---------- f16 weight region offsets (in _Float16 units), lives in d_ws ----------
constexpr int O_AW0H = 0;        // 256x128
constexpr int O_AW1H = 32768;    // 128x128
constexpr int O_AW2H = 49152;
constexpr int O_AW3H = 65536;    // 128x256
constexpr int O_PW0H = 98304;
constexpr int O_PW1H = 131072;
constexpr int O_PW2H = 147456;
constexpr int O_PW3H = 163840;   // 128x16
constexpr int O_AW1L = 165888;
constexpr int O_AW2L = 182272;
constexpr int O_AW3L = 198656;

// ---------- weight prep: transpose + split f32 -> f16 hi/lo ----------
struct PrepJob { const float* src; _Float16* h; _Float16* l; int nshift; int total; };
struct PrepJobs { PrepJob j[8]; };

__global__ void prep_kernel(PrepJobs js){
  const PrepJob jb = js.j[blockIdx.y];
  const int idx = blockIdx.x*256 + threadIdx.x;
  if (idx >= jb.total) return;
  const int N = 1 << jb.nshift;
  const int n = idx & (N-1);           // fastest-varying -> coalesced src read
  const int k = idx >> jb.nshift;
  const int K = jb.total >> jb.nshift;
  float w = jb.src[idx];               // src[k*N + n] == src[idx]
  _Float16 h = (_Float16)w;
  jb.h[(long)n*K + k] = h;
  if (jb.l) jb.l[(long)n*K + k] = (_Float16)(w - (float)h);
}

// ---------- LDS activation layout: 64 rows x 128 cols of packed (hi|lo) u32 ----------
// 16B-chunk XOR swizzle by (row&7)
__device__ __forceinline__ int aaddr(int row, int col){
  int cc = (col >> 2) ^ (row & 7);
  return row*128 + (cc<<2) + (col & 3);
}

template<bool NEED_LO>
__device__ __forceinline__ void read_frag(const unsigned int* __restrict__ act,
    int row, int ks, int q, half8& ah, half8& al)
{
  const int s = row & 7;
  const int cc0 = ks*8 + q*2;
  uint4v c0 = *(const uint4v*)(act + row*128 + (((cc0  ) ^ s)<<2));
  uint4v c1 = *(const uint4v*)(act + row*128 + (((cc0+1) ^ s)<<2));
  uint4v h;
  h.x = (c0.x & 0xffffu) | (c0.y << 16);
  h.y = (c0.z & 0xffffu) | (c0.w << 16);
  h.z = (c1.x & 0xffffu) | (c1.y << 16);
  h.w = (c1.z & 0xffffu) | (c1.w << 16);
  ah = __builtin_bit_cast(half8, h);
  if constexpr (NEED_LO){
    uint4v g;
    g.x = (c0.x >> 16) | (c0.y & 0xffff0000u);
    g.y = (c0.z >> 16) | (c0.w & 0xffff0000u);
    g.z = (c1.x >> 16) | (c1.y & 0xffff0000u);
    g.w = (c1.z >> 16) | (c1.w & 0xffff0000u);
    al = __builtin_bit_cast(half8, g);
  }
}

__device__ __forceinline__ unsigned int pack_act(float v){
  _Float16 h = (_Float16)v;
  _Float16 lo = (_Float16)(v - (float)h);
  return (unsigned int)__builtin_bit_cast(unsigned short, h)
       | ((unsigned int)__builtin_bit_cast(unsigned short, lo) << 16);
}
__device__ __forceinline__ unsigned int pack_act_hi(float v){
  return (unsigned int)__builtin_bit_cast(unsigned short, (_Float16)v);
}

// ---------- load one weight tile's fragments into a register stage ----------
template<int KS, bool LO>
__device__ __forceinline__ void load_tile(
    const _Float16* __restrict__ Wh, const _Float16* __restrict__ Wl,
    int K, int nt, int l15, int q, half8* bh, half8* bl)
{
  const _Float16* bp = Wh + (nt*16 + l15)*K + q*8;
#pragma unroll
  for (int ks=0; ks<KS; ++ks) bh[ks] = *(const half8*)(bp + ks*32);
  if constexpr (LO){
    const _Float16* blp = Wl + (nt*16 + l15)*K + q*8;
#pragma unroll
    for (int ks=0; ks<KS; ++ks) bl[ks] = *(const half8*)(blp + ks*32);
  }
}

// ---------- QUAD m-tile MFMA stream: each loaded B-frag feeds 4 MFMAs ----------
// Per tile-slot: [issue loads nt+RING-1] -> [MFMAs for 4 m-tiles, 4 independent
// acc chains] -> [epi(nt)]. 4x arithmetic intensity per loaded weight byte.
template<int KS, int PASSES, int NT, int RING, typename EPI>
__device__ __forceinline__ void mfma_stream4(
    const half8 (&Ah)[4][KS], const half8 (&Al)[4][KS],
    const _Float16* __restrict__ Wh, const _Float16* __restrict__ Wl,
    int K, int l15, int q, EPI&& epi)
{
  half8 Bh[RING][KS], Bl[RING][KS];
  load_tile<KS,PASSES==3>(Wh, Wl, K, 0, l15, q, Bh[0], Bl[0]);
  if constexpr (RING > 2){
    if constexpr (NT > 1)
      load_tile<KS,PASSES==3>(Wh, Wl, K, 1, l15, q, Bh[1], Bl[1]);
  }
#pragma unroll
  for (int nt=0; nt<NT; ++nt){
    constexpr int PD = RING - 1;
    if (nt+PD < NT)
      load_tile<KS,PASSES==3>(Wh, Wl, K, nt+PD, l15, q, Bh[(nt+PD)%RING], Bl[(nt+PD)%RING]);
    floatx4 acc[4];
#pragma unroll
    for (int m=0; m<4; ++m) acc[m] = (floatx4)0.0f;
#pragma unroll
    for (int ks=0; ks<KS; ++ks){
      const half8 bh = Bh[nt%RING][ks];
#pragma unroll
      for (int m=0; m<4; ++m)
        acc[m] = MFMA16(Ah[m][ks], bh, acc[m]);
      if constexpr (PASSES == 3){
        const half8 bl = Bl[nt%RING][ks];
#pragma unroll
        for (int m=0; m<4; ++m){
          acc[m] = MFMA16(Al[m][ks], bh, acc[m]);
          acc[m] = MFMA16(Ah[m][ks], bl, acc[m]);
        }
      }
    }
    epi(nt, acc);
  }
}

// ================= Fused kernel: MLPs + Sinkhorn + payments =================
// 64 threads = 1 wave per block, 64 rows/block (4 m-tiles). Zero barriers.
// LDS map: S[0..8192) = act_a (64x128 u32 hi|lo), S[8192..16384) = act_p,
//          S[0..16384) REUSED as aug f32 (64 rows x 256) after pL4 + aL4 pre-read.
//          S[16384..17408) = frac f32 (64x16).  Total 69632 B -> 2 blocks/CU.
// __launch_bounds__(64,1): only 2 waves/CU (LDS-capped), so up to ~500 VGPR/wave
// are free — the 4-m-tile A-fragment set (128 VGPR) carries no spill risk.
__global__ __launch_bounds__(64, 1) void fused_kernel(
  const float* __restrict__ X, const _Float16* __restrict__ WT,
  const float* __restrict__ ab0, const float* __restrict__ ab1,
  const float* __restrict__ ab2, const float* __restrict__ ab3,
  const float* __restrict__ pb0, const float* __restrict__ pb1,
  const float* __restrict__ pb2, const float* __restrict__ pb3,
  float* __restrict__ out)
{
  __shared__ unsigned int S[64*256 + 1024];   // 69632 B
  unsigned int* act_a = S;
  unsigned int* act_p = S + 8192;
  float* frac_l = (float*)(S + 16384);
  const int l = threadIdx.x, q = l>>4, l15 = l&15;
  const long rb = (long)blockIdx.x * 64;

  // per-tile epilogue maker: bias+tanh+pack all 4 m-tiles
  auto epi_act = [&](unsigned int* act, const float* bias, bool lo){
    return [=](int nt, auto& acc){
      float bb = bias[nt*16 + l15];
#pragma unroll
      for (int m=0; m<4; ++m){
#pragma unroll
        for (int r=0; r<4; ++r){
          float t = tanh_f(acc[m][r] + bb);
          act[aaddr(m*16 + q*4 + r, nt*16 + l15)] = lo ? pack_act(t) : pack_act_hi(t);
        }
      }
    };
  };

  // ---- L1 of both nets: X frags for all 4 m-tiles (K=256) ----
  {
    half8 Xf[4][8];
#pragma unroll
    for (int mt=0; mt<4; ++mt){
      float4 xa[8], xb[8];
#pragma unroll
      for (int ks=0; ks<8; ++ks){
        const float* xp = X + (rb + mt*16 + l15)*256 + ks*32 + q*8;
        xa[ks] = *(const float4*)(xp);
        xb[ks] = *(const float4*)(xp + 4);
      }
#pragma unroll
      for (int ks=0; ks<8; ++ks){
        half8 h;
        h[0]=(_Float16)xa[ks].x; h[1]=(_Float16)xa[ks].y; h[2]=(_Float16)xa[ks].z; h[3]=(_Float16)xa[ks].w;
        h[4]=(_Float16)xb[ks].x; h[5]=(_Float16)xb[ks].y; h[6]=(_Float16)xb[ks].z; h[7]=(_Float16)xb[ks].w;
        Xf[mt][ks] = h;
      }
    }
    mfma_stream4<8,1,8,2>(Xf, Xf, WT+O_AW0H, WT+O_AW0H, 256, l15, q,
                          epi_act(act_a, ab0, true));
    mfma_stream4<8,1,8,2>(Xf, Xf, WT+O_PW0H, WT+O_PW0H, 256, l15, q,
                          epi_act(act_p, pb0, false));
  }

  // ---- hidden layers: a (3-pass hi/lo), p (1-pass) ----
  {
    half8 Ah[4][4], Al[4][4];
#pragma unroll
    for (int m=0; m<4; ++m)
#pragma unroll
      for (int ks=0; ks<4; ++ks)
        read_frag<true>(act_a, m*16 + l15, ks, q, Ah[m][ks], Al[m][ks]);
    mfma_stream4<4,3,8,2>(Ah, Al, WT+O_AW1H, WT+O_AW1L, 128, l15, q,
                          epi_act(act_a, ab1, true));
  }
  {
    half8 Ph[4][4], du;
#pragma unroll
    for (int m=0; m<4; ++m)
#pragma unroll
      for (int ks=0; ks<4; ++ks)
        read_frag<false>(act_p, m*16 + l15, ks, q, Ph[m][ks], du);
    mfma_stream4<4,1,8,3>(Ph, Ph, WT+O_PW1H, WT+O_PW1H, 128, l15, q,
                          epi_act(act_p, pb1, false));
  }
  {
    half8 Ah[4][4], Al[4][4];
#pragma unroll
    for (int m=0; m<4; ++m)
#pragma unroll
      for (int ks=0; ks<4; ++ks)
        read_frag<true>(act_a, m*16 + l15, ks, q, Ah[m][ks], Al[m][ks]);
    mfma_stream4<4,3,8,2>(Ah, Al, WT+O_AW2H, WT+O_AW2L, 128, l15, q,
                          epi_act(act_a, ab2, true));
  }
  {
    half8 Ph[4][4], du;
#pragma unroll
    for (int m=0; m<4; ++m)
#pragma unroll
      for (int ks=0; ks<4; ++ks)
        read_frag<false>(act_p, m*16 + l15, ks, q, Ph[m][ks], du);
    mfma_stream4<4,1,8,3>(Ph, Ph, WT+O_PW2H, WT+O_PW2H, 128, l15, q,
                          epi_act(act_p, pb2, false));
  }

  // ---- p-net L4 -> frac (sigmoid) to LDS — MUST precede aL4's aug overlay ----
  {
    half8 Ph[4][4], du;
#pragma unroll
    for (int m=0; m<4; ++m)
#pragma unroll
      for (int ks=0; ks<4; ++ks)
        read_frag<false>(act_p, m*16 + l15, ks, q, Ph[m][ks], du);
    mfma_stream4<4,1,1,2>(Ph, Ph, WT+O_PW3H, WT+O_PW3H, 128, l15, q,
      [&](int, auto& acc){
        float bb = pb3[l15];
#pragma unroll
        for (int m=0; m<4; ++m)
#pragma unroll
          for (int r=0; r<4; ++r)
            frac_l[(m*16 + q*4 + r)*16 + l15] = sigmoid_f(acc[m][r] + bb);
      });
  }
  // ---- a-net L4 -> aug (f32) into LDS overlay; act_a fully pre-read to regs ----
  {
    half8 Ah[4][4], Al[4][4];
#pragma unroll
    for (int m=0; m<4; ++m)
#pragma unroll
      for (int ks=0; ks<4; ++ks)
        read_frag<true>(act_a, m*16 + l15, ks, q, Ah[m][ks], Al[m][ks]);
    float* augl = (float*)S;
#pragma unroll
    for (int hf=0; hf<2; ++hf){
      const int ncol0 = hf*128;
      mfma_stream4<4,3,8,2>(Ah, Al,
                            WT+O_AW3H + hf*128*128, WT+O_AW3L + hf*128*128,
                            128, l15, q,
        [&](int nt, auto& acc){
          float bb = ab3[ncol0 + nt*16 + l15];
#pragma unroll
          for (int m=0; m<4; ++m)
#pragma unroll
            for (int r=0; r<4; ++r)
              augl[(m*16 + q*4 + r)*256 + ncol0 + nt*16 + l15] = acc[m][r] + bb;
        });
    }
  }

  // ================= Sinkhorn + payments: four sequential 16-element passes ===
  // Lane owns 4 columns (4c..4c+3) of element eL = mt*16 + (l>>2).
  const int c = l & 3;
  const float Ssc = 14.426950408889634f; // (1/EPS)/ln2 : logits in exp2 units
  const float cmask = (c == 3) ? 1.0f : 0.0f;

#pragma unroll 1
  for (int mt=0; mt<4; ++mt){
    const int eL = mt*16 + (l >> 2);
    const long e = rb + eL;

    floatx2 Kp[4][8];   // owned columns, rows (2k, 2k+1)
    floatx2 KPp[8];     // pad column 16 (lane 3 only; zero elsewhere), row-pairs

    const float* ap = (const float*)S + eL*256 + 4*c;
#pragma unroll
    for (int k=0;k<8;++k){
      float4 va = *(const float4*)(ap + (2*k  )*16);
      float4 vb = *(const float4*)(ap + (2*k+1)*16);
      Kp[0][k] = (floatx2){va.x*Ssc, vb.x*Ssc};
      Kp[1][k] = (floatx2){va.y*Ssc, vb.y*Ssc};
      Kp[2][k] = (floatx2){va.z*Ssc, vb.z*Ssc};
      Kp[3][k] = (floatx2){va.w*Ssc, vb.w*Ssc};
    }

    // max-subtract + exponentiate (row-wise, across the 4 lanes + pad col 0)
#pragma unroll
    for (int k=0;k<8;++k){
      float m0 = fmaxf(fmaxf(Kp[0][k].x,Kp[1][k].x), fmaxf(Kp[2][k].x,Kp[3][k].x));
      m0 = qmax2(fmaxf(m0, 0.0f));
      float m1 = fmaxf(fmaxf(Kp[0][k].y,Kp[1][k].y), fmaxf(Kp[2][k].y,Kp[3][k].y));
      m1 = qmax2(fmaxf(m1, 0.0f));
      Kp[0][k] = (floatx2){exp2_f(Kp[0][k].x-m0), exp2_f(Kp[0][k].y-m1)};
      Kp[1][k] = (floatx2){exp2_f(Kp[1][k].x-m0), exp2_f(Kp[1][k].y-m1)};
      Kp[2][k] = (floatx2){exp2_f(Kp[2][k].x-m0), exp2_f(Kp[2][k].y-m1)};
      Kp[3][k] = (floatx2){exp2_f(Kp[3][k].x-m0), exp2_f(Kp[3][k].y-m1)};
      KPp[k]   = (floatx2){cmask*exp2_f(-m0), cmask*exp2_f(-m1)};
    }
    // row 16: logits all 0, row max = 0 -> K entries exactly 1 (pad col: cmask)

    float vj0=1.f, vj1=1.f, vj2=1.f, vj3=1.f;
    float v16 = cmask;
    floatx2 u2[8];
    float u16;

    for (int r=0;r<40;++r){
      floatx2 b0=(floatx2){vj0,vj0}, b1=(floatx2){vj1,vj1};
      floatx2 b2=(floatx2){vj2,vj2}, b3=(floatx2){vj3,vj3};
      floatx2 b16=(floatx2){v16,v16};
      // ---- row normalization: u_i = 1 / sum_j K_ij v_j ----
#pragma unroll
      for (int k=0;k<8;++k){
        floatx2 pp = pk_mul2(Kp[0][k], b0);
        pp = pk_fma2(Kp[1][k], b1, pp);
        pp = pk_fma2(Kp[2][k], b2, pp);
        pp = pk_fma2(Kp[3][k], b3, pp);
        pp = pk_fma2(KPp[k], b16, pp);
        float px = qadd2(pp.x);
        float py = qadd2(pp.y);
        u2[k] = (floatx2){rcp_f(px), rcp_f(py)};
      }
      {
        // row 16: K == 1 across real cols, cmask on pad col; a_16 = I = 16
        float p16 = (vj0+vj1) + (vj2+vj3) + cmask*v16;
        p16 = qadd2(p16);
        u16 = 16.0f * rcp_f(p16);
      }
      // ---- column normalization: v_j = 1 / sum_i K_ij u_i ----
      floatx2 t0p = pk_mul2(Kp[0][0], u2[0]);
      floatx2 t1p = pk_mul2(Kp[1][0], u2[0]);
      floatx2 t2p = pk_mul2(Kp[2][0], u2[0]);
      floatx2 t3p = pk_mul2(Kp[3][0], u2[0]);
      floatx2 tPp = pk_mul2(KPp[0],   u2[0]);
#pragma unroll
      for (int k=1;k<8;++k){
        t0p = pk_fma2(Kp[0][k], u2[k], t0p);
        t1p = pk_fma2(Kp[1][k], u2[k], t1p);
        t2p = pk_fma2(Kp[2][k], u2[k], t2p);
        t3p = pk_fma2(Kp[3][k], u2[k], t3p);
        tPp = pk_fma2(KPp[k],   u2[k], tPp);
      }
      float t0 = t0p.x + t0p.y + u16;        // row-16 K == 1
      float t1 = t1p.x + t1p.y + u16;
      float t2 = t2p.x + t2p.y + u16;
      float t3 = t3p.x + t3p.y + u16;
      float t16 = tPp.x + tPp.y + cmask*u16;
      vj0 = rcp_f(t0); vj1 = rcp_f(t1); vj2 = rcp_f(t2); vj3 = rcp_f(t3);
      v16 = cmask * 16.0f * rcp_f(t16 + 1e-30f + (1.0f - cmask));  // b_16 = A = 16; NaN-guard off-lane
    }

    // ---- allocs = u_i K_ij v_j (write) + payments dot fused (reuse w) ----
    float* op = out + e*256 + 4*c;
    const float* bpx = X + e*256 + 4*c;
    float pv0=0.f, pv1=0.f, pv2=0.f, pv3=0.f;
#pragma unroll
    for (int k=0;k<8;++k){
#pragma unroll
      for (int h=0;h<2;++h){
        const int i = 2*k + h;
        const float uu = h ? u2[k].y : u2[k].x;
        const float K0 = h ? Kp[0][k].y : Kp[0][k].x;
        const float K1 = h ? Kp[1][k].y : Kp[1][k].x;
        const float K2 = h ? Kp[2][k].y : Kp[2][k].x;
        const float K3 = h ? Kp[3][k].y : Kp[3][k].x;
        float4 w;
        w.x = uu*K0*vj0;
        w.y = uu*K1*vj1;
        w.z = uu*K2*vj2;
        w.w = uu*K3*vj3;
        *(float4*)(op + i*16) = w;
        float4 bb = *(const float4*)(bpx + i*16);
        float s = w.x*bb.x + w.y*bb.y + w.z*bb.z + w.w*bb.w;
        s = qadd2(s);
        if ((i>>2) == c){
          const int rr = i & 3;
          if      (rr==0) pv0 = s;
          else if (rr==1) pv1 = s;
          else if (rr==2) pv2 = s;
          else            pv3 = s;
        }
      }
    }
    const float4 fr = *(const float4*)(frac_l + eL*16 + 4*c);
    float4 pvv;
    pvv.x = pv0*fr.x; pvv.y = pv1*fr.y; pvv.z = pv2*fr.z; pvv.w = pv3*fr.w;
    *(float4*)(out + (size_t)NB*256 + e*16 + 4*c) = pvv;
  }
}

// ================= launch =================
extern "C" void kernel_launch(void* const* d_in, const int* in_sizes, int n_in,
                              void* d_out, int out_size, void* d_ws, size_t ws_size,
                              hipStream_t stream)
{
  const float* bids = (const float*)d_in[0];
  const float* aw0 = (const float*)d_in[1];  const float* ab0 = (const float*)d_in[2];
  const float* aw1 = (const float*)d_in[3];  const float* ab1 = (const float*)d_in[4];
  const float* aw2 = (const float*)d_in[5];  const float* ab2 = (const float*)d_in[6];
  const float* aw3 = (const float*)d_in[7];  const float* ab3 = (const float*)d_in[8];
  const float* pw0 = (const float*)d_in[9];  const float* pb0 = (const float*)d_in[10];
  const float* pw1 = (const float*)d_in[11]; const float* pb1 = (const float*)d_in[12];
  const float* pw2 = (const float*)d_in[13]; const float* pb2 = (const float*)d_in[14];
  const float* pw3 = (const float*)d_in[15]; const float* pb3 = (const float*)d_in[16];

  _Float16* WT = (_Float16*)d_ws;

  // nshift = log2(N) where W is K x N (row-major src); dst is N x K (transposed)
  PrepJobs js;
  js.j[0] = { aw0, WT+O_AW0H, nullptr,    7, 32768 };  // 256x128
  js.j[1] = { aw1, WT+O_AW1H, WT+O_AW1L,  7, 16384 };  // 128x128
  js.j[2] = { aw2, WT+O_AW2H, WT+O_AW2L,  7, 16384 };  // 128x128
  js.j[3] = { aw3, WT+O_AW3H, WT+O_AW3L,  8, 32768 };  // 128x256
  js.j[4] = { pw0, WT+O_PW0H, nullptr,    7, 32768 };  // 256x128
  js.j[5] = { pw1, WT+O_PW1H, nullptr,    7, 16384 };  // 128x128
  js.j[6] = { pw2, WT+O_PW2H, nullptr,    7, 16384 };  // 128x128
  js.j[7] = { pw3, WT+O_PW3H, nullptr,    4, 2048  };  // 128x16

  prep_kernel<<<dim3(128,8), 256, 0, stream>>>(js);
  fused_kernel<<<dim3(NB/64), 64, 0, stream>>>(bids, WT, ab0,ab1,ab2,ab3,
                                               pb0,pb1,pb2,pb3, (float*)d_out);
}

// Round 7
// 198.697 us; speedup vs baseline: 1.3014x; 1.3014x over previous
//
#include <hip/hip_runtime.h>

#define NB 32768

typedef _Float16 half8 __attribute__((ext_vector_type(8)));
typedef float floatx4 __attribute__((ext_vector_type(4)));
typedef float floatx2 __attribute__((ext_vector_type(2)));
typedef unsigned int uint4v __attribute__((ext_vector_type(4)));

#define MFMA16(a,b,c) __builtin_amdgcn_mfma_f32_16x16x32_f16(a,b,c,0,0,0)

// ---------- fast math ----------
__device__ __forceinline__ float rcp_f(float x){ return __builtin_amdgcn_rcpf(x); }
__device__ __forceinline__ float exp2_f(float x){ return __builtin_amdgcn_exp2f(x); }
__device__ __forceinline__ float tanh_f(float x){
  float e = exp2_f(x * 2.8853900817779268f);     // e^(2x)
  return (e - 1.0f) * rcp_f(e + 1.0f);
}
__device__ __forceinline__ float sigmoid_f(float x){
  return rcp_f(1.0f + exp2_f(-1.4426950408889634f * x));
}

// packed f32 math (VOP3P)
__device__ __forceinline__ floatx2 pk_mul2(floatx2 a, floatx2 b){
  floatx2 d; asm("v_pk_mul_f32 %0, %1, %2" : "=v"(d) : "v"(a), "v"(b)); return d;
}
__device__ __forceinline__ floatx2 pk_fma2(floatx2 a, floatx2 b, floatx2 c){
  floatx2 d; asm("v_pk_fma_f32 %0, %1, %2, %3" : "=v"(d) : "v"(a), "v"(b), "v"(c)); return d;
}

// DPP quad butterflies: xor1 = quad_perm[1,0,3,2]=0xB1, xor2 = [2,3,0,1]=0x4E
template<int CTRL>
__device__ __forceinline__ float dpp_qp(float x){
  return __builtin_bit_cast(float, __builtin_amdgcn_update_dpp(0, __builtin_bit_cast(int,x), CTRL, 0xF, 0xF, true));
}
__device__ __forceinline__ float qadd2(float x){
  x += dpp_qp<0xB1>(x);
  x += dpp_qp<0x4E>(x);
  return x;
}
__device__ __forceinline__ float qmax2(float x){
  x = fmaxf(x, dpp_qp<0xB1>(x));
  x = fmaxf(x, dpp_qp<0x4E>(x));
  return x;
}

// ---------- f16 weight region offsets (in _Float16 units), lives in d_ws ----------
constexpr int O_AW0H = 0;        // 256x128
constexpr int O_AW1H = 32768;    // 128x128
constexpr int O_AW2H = 49152;
constexpr int O_AW3H = 65536;    // 128x256
constexpr int O_PW0H = 98304;
constexpr int O_PW1H = 131072;
constexpr int O_PW2H = 147456;
constexpr int O_PW3H = 163840;   // 128x16
constexpr int O_AW1L = 165888;
constexpr int O_AW2L = 182272;
constexpr int O_AW3L = 198656;

// ---------- weight prep: transpose + split f32 -> f16 hi/lo ----------
struct PrepJob { const float* src; _Float16* h; _Float16* l; int nshift; int total; };
struct PrepJobs { PrepJob j[8]; };

__global__ void prep_kernel(PrepJobs js){
  const PrepJob jb = js.j[blockIdx.y];
  const int idx = blockIdx.x*256 + threadIdx.x;
  if (idx >= jb.total) return;
  const int N = 1 << jb.nshift;
  const int n = idx & (N-1);           // fastest-varying -> coalesced src read
  const int k = idx >> jb.nshift;
  const int K = jb.total >> jb.nshift;
  float w = jb.src[idx];               // src[k*N + n] == src[idx]
  _Float16 h = (_Float16)w;
  jb.h[(long)n*K + k] = h;
  if (jb.l) jb.l[(long)n*K + k] = (_Float16)(w - (float)h);
}

// ---------- LDS activation layout: 32 rows x 128 cols of packed (hi|lo) u32 ----------
// 16B-chunk XOR swizzle by (row&7)
__device__ __forceinline__ int aaddr(int row, int col){
  int cc = (col >> 2) ^ (row & 7);
  return row*128 + (cc<<2) + (col & 3);
}

template<bool NEED_LO>
__device__ __forceinline__ void read_frag(const unsigned int* __restrict__ act,
    int row, int ks, int q, half8& ah, half8& al)
{
  const int s = row & 7;
  const int cc0 = ks*8 + q*2;
  uint4v c0 = *(const uint4v*)(act + row*128 + (((cc0  ) ^ s)<<2));
  uint4v c1 = *(const uint4v*)(act + row*128 + (((cc0+1) ^ s)<<2));
  uint4v h;
  h.x = (c0.x & 0xffffu) | (c0.y << 16);
  h.y = (c0.z & 0xffffu) | (c0.w << 16);
  h.z = (c1.x & 0xffffu) | (c1.y << 16);
  h.w = (c1.z & 0xffffu) | (c1.w << 16);
  ah = __builtin_bit_cast(half8, h);
  if constexpr (NEED_LO){
    uint4v g;
    g.x = (c0.x >> 16) | (c0.y & 0xffff0000u);
    g.y = (c0.z >> 16) | (c0.w & 0xffff0000u);
    g.z = (c1.x >> 16) | (c1.y & 0xffff0000u);
    g.w = (c1.z >> 16) | (c1.w & 0xffff0000u);
    al = __builtin_bit_cast(half8, g);
  }
}

__device__ __forceinline__ unsigned int pack_act(float v){
  _Float16 h = (_Float16)v;
  _Float16 lo = (_Float16)(v - (float)h);
  return (unsigned int)__builtin_bit_cast(unsigned short, h)
       | ((unsigned int)__builtin_bit_cast(unsigned short, lo) << 16);
}
__device__ __forceinline__ unsigned int pack_act_hi(float v){
  return (unsigned int)__builtin_bit_cast(unsigned short, (_Float16)v);
}

// ---------- load one weight tile's fragments into a register stage ----------
template<int KS, bool LO>
__device__ __forceinline__ void load_tile(
    const _Float16* __restrict__ Wh, const _Float16* __restrict__ Wl,
    int K, int nt, int l15, int q, half8* bh, half8* bl)
{
  const _Float16* bp = Wh + (nt*16 + l15)*K + q*8;
#pragma unroll
  for (int ks=0; ks<KS; ++ks) bh[ks] = *(const half8*)(bp + ks*32);
  if constexpr (LO){
    const _Float16* blp = Wl + (nt*16 + l15)*K + q*8;
#pragma unroll
    for (int ks=0; ks<KS; ++ks) bl[ks] = *(const half8*)(blp + ks*32);
  }
}

// ---------- DUAL m-tile MFMA stream over n-tiles nt0..nt0+NT-1 ----------
// Per tile-slot: [issue loads] -> [MFMAs both m-tiles] -> [epi]. Ring prefetch.
template<int KS, int PASSES, int NT, int RING, typename EPI>
__device__ __forceinline__ void mfma_stream2(
    const half8* Ah0, const half8* Al0,
    const half8* Ah1, const half8* Al1,
    const _Float16* __restrict__ Wh, const _Float16* __restrict__ Wl,
    int K, int nt0, int l15, int q, EPI&& epi)
{
  half8 Bh[RING][KS], Bl[RING][KS];
  load_tile<KS,PASSES==3>(Wh, Wl, K, nt0, l15, q, Bh[0], Bl[0]);
  if constexpr (RING > 2){
    if constexpr (NT > 1)
      load_tile<KS,PASSES==3>(Wh, Wl, K, nt0+1, l15, q, Bh[1], Bl[1]);
  }
#pragma unroll
  for (int nt=0; nt<NT; ++nt){
    constexpr int PD = RING - 1;
    if (nt+PD < NT)
      load_tile<KS,PASSES==3>(Wh, Wl, K, nt0+nt+PD, l15, q, Bh[(nt+PD)%RING], Bl[(nt+PD)%RING]);
    floatx4 a0e=(floatx4)0.0f, a0o=(floatx4)0.0f;
    floatx4 a1e=(floatx4)0.0f, a1o=(floatx4)0.0f;
#pragma unroll
    for (int ks=0; ks<KS; ++ks){
      const half8 bh = Bh[nt%RING][ks];
      floatx4& c0 = (ks & 1) ? a0o : a0e;
      floatx4& c1 = (ks & 1) ? a1o : a1e;
      c0 = MFMA16(Ah0[ks], bh, c0);
      c1 = MFMA16(Ah1[ks], bh, c1);
      if constexpr (PASSES == 3){
        const half8 bl = Bl[nt%RING][ks];
        c0 = MFMA16(Al0[ks], bh, c0);
        c0 = MFMA16(Ah0[ks], bl, c0);
        c1 = MFMA16(Al1[ks], bh, c1);
        c1 = MFMA16(Ah1[ks], bl, c1);
      }
    }
    floatx4 acc0, acc1;
#pragma unroll
    for (int r=0; r<4; ++r){ acc0[r] = a0e[r] + a0o[r]; acc1[r] = a1e[r] + a1o[r]; }
    epi(nt0+nt, acc0, acc1);
  }
}

// ================= Fused kernel: MLPs + Sinkhorn + payments =================
// 128 threads = 2 waves per block, 32 rows/block (2 m-tiles). N-SPLIT: wave w
// computes output cols w*64..w*64+63 (n-tiles w*4..w*4+3) of every layer ->
// per-wave weight loads/MFMA/epi/Sinkhorn all HALF of round-5's wave, at
// 2 waves/SIMD (8 waves/CU) for latency hiding. Barrier discipline per stage:
// [read act frags to regs] -> bar -> [mfma + epi own cols] -> bar.
// LDS map: S[0..4096) = act_a (32x128 u32 hi|lo), S[4096..8192) = act_p,
//          S[0..8192) REUSED as aug f32 (32x256) after final-stage pre-reads.
//          S[8192..8704) = frac f32 (32x16). Total 34816 B -> 4 blocks/CU.
__global__ __launch_bounds__(128, 2) void fused_kernel(
  const float* __restrict__ X, const _Float16* __restrict__ WT,
  const float* __restrict__ ab0, const float* __restrict__ ab1,
  const float* __restrict__ ab2, const float* __restrict__ ab3,
  const float* __restrict__ pb0, const float* __restrict__ pb1,
  const float* __restrict__ pb2, const float* __restrict__ pb3,
  float* __restrict__ out)
{
  __shared__ unsigned int S[32*256 + 512];   // 34816 B
  unsigned int* act_a = S;
  unsigned int* act_p = S + 4096;
  float* frac_l = (float*)(S + 8192);
  const int t = threadIdx.x;
  const int w = t >> 6;                      // wave id 0/1
  const int l = t & 63, q = l>>4, l15 = l&15;
  const int nt0 = w*4;                       // this wave's n-tile base
  const long rb = (long)blockIdx.x * 32;

  // per-tile epilogue maker: bias+tanh+pack both m-tiles at global n-tile ntg
  auto epi_act = [&](unsigned int* act, const float* bias, bool lo){
    return [=](int ntg, floatx4 acc0, floatx4 acc1){
      float bb = bias[ntg*16 + l15];
#pragma unroll
      for (int r=0; r<4; ++r){
        float t0 = tanh_f(acc0[r] + bb);
        act[aaddr(q*4 + r, ntg*16 + l15)] = lo ? pack_act(t0) : pack_act_hi(t0);
      }
#pragma unroll
      for (int r=0; r<4; ++r){
        float t1 = tanh_f(acc1[r] + bb);
        act[aaddr(16 + q*4 + r, ntg*16 + l15)] = lo ? pack_act(t1) : pack_act_hi(t1);
      }
    };
  };

  // ---- L1 of both nets: X frags for both m-tiles (K=256), own 4 n-tiles ----
  {
    half8 Xf0[8], Xf1[8];
#pragma unroll
    for (int mt=0; mt<2; ++mt){
      float4 xa[8], xb[8];
#pragma unroll
      for (int ks=0; ks<8; ++ks){
        const float* xp = X + (rb + mt*16 + l15)*256 + ks*32 + q*8;
        xa[ks] = *(const float4*)(xp);
        xb[ks] = *(const float4*)(xp + 4);
      }
      half8* Xf = mt ? Xf1 : Xf0;
#pragma unroll
      for (int ks=0; ks<8; ++ks){
        half8 h;
        h[0]=(_Float16)xa[ks].x; h[1]=(_Float16)xa[ks].y; h[2]=(_Float16)xa[ks].z; h[3]=(_Float16)xa[ks].w;
        h[4]=(_Float16)xb[ks].x; h[5]=(_Float16)xb[ks].y; h[6]=(_Float16)xb[ks].z; h[7]=(_Float16)xb[ks].w;
        Xf[ks] = h;
      }
    }
    mfma_stream2<8,1,4,2>(Xf0, Xf0, Xf1, Xf1, WT+O_AW0H, WT+O_AW0H, 256, nt0, l15, q,
                          epi_act(act_a, ab0, true));
    mfma_stream2<8,1,4,2>(Xf0, Xf0, Xf1, Xf1, WT+O_PW0H, WT+O_PW0H, 256, nt0, l15, q,
                          epi_act(act_p, pb0, false));
  }
  __syncthreads();

  // ---- hidden stages: [read all frags] bar [mfma+epi own cols] bar ----
#pragma unroll 1
  for (int st=0; st<2; ++st){
    const _Float16* Wah = WT + (st ? O_AW2H : O_AW1H);
    const _Float16* Wal = WT + (st ? O_AW2L : O_AW1L);
    const _Float16* Wph = WT + (st ? O_PW2H : O_PW1H);
    const float* ba = st ? ab2 : ab1;
    const float* bp = st ? pb2 : pb1;
    half8 Aa0[4], Ala0[4], Aa1[4], Ala1[4], Ap0[4], Ap1[4], du;
#pragma unroll
    for (int ks=0; ks<4; ++ks){
      read_frag<true >(act_a, l15,      ks, q, Aa0[ks], Ala0[ks]);
      read_frag<true >(act_a, 16 + l15, ks, q, Aa1[ks], Ala1[ks]);
      read_frag<false>(act_p, l15,      ks, q, Ap0[ks], du);
      read_frag<false>(act_p, 16 + l15, ks, q, Ap1[ks], du);
    }
    __syncthreads();
    mfma_stream2<4,3,4,2>(Aa0, Ala0, Aa1, Ala1, Wah, Wal, 128, nt0, l15, q,
                          epi_act(act_a, ba, true));
    mfma_stream2<4,1,4,3>(Ap0, Ap0, Ap1, Ap1, Wph, Wph, 128, nt0, l15, q,
                          epi_act(act_p, bp, false));
    __syncthreads();
  }

  // ---- final stage: pL4 (wave 0, both m-tiles) + aL4 half hf=w -> aug ----
  {
    half8 Aa0[4], Ala0[4], Aa1[4], Ala1[4], Ap0[4], Ap1[4], du;
#pragma unroll
    for (int ks=0; ks<4; ++ks){
      read_frag<true>(act_a, l15,      ks, q, Aa0[ks], Ala0[ks]);
      read_frag<true>(act_a, 16 + l15, ks, q, Aa1[ks], Ala1[ks]);
    }
    if (w == 0){
#pragma unroll
      for (int ks=0; ks<4; ++ks){
        read_frag<false>(act_p, l15,      ks, q, Ap0[ks], du);
        read_frag<false>(act_p, 16 + l15, ks, q, Ap1[ks], du);
      }
    }
    __syncthreads();
    if (w == 0){
      mfma_stream2<4,1,1,2>(Ap0, Ap0, Ap1, Ap1, WT+O_PW3H, WT+O_PW3H, 128, 0, l15, q,
        [&](int, floatx4 a0, floatx4 a1){
          float bb = pb3[l15];
#pragma unroll
          for (int r=0; r<4; ++r){
            frac_l[(q*4+r)*16 + l15]    = sigmoid_f(a0[r] + bb);
            frac_l[(16+q*4+r)*16 + l15] = sigmoid_f(a1[r] + bb);
          }
        });
    }
    // aug half hf = w (cols w*128..w*128+127) overlays act_a/act_p (reads done)
    float* augl = (float*)S;
    const int ncol0 = w*128;
    mfma_stream2<4,3,8,2>(Aa0, Ala0, Aa1, Ala1,
                          WT+O_AW3H + w*128*128, WT+O_AW3L + w*128*128,
                          128, 0, l15, q,
      [&](int nt, floatx4 a0, floatx4 a1){
        float bb = ab3[ncol0 + nt*16 + l15];
#pragma unroll
        for (int r=0; r<4; ++r){
          augl[(q*4+r)*256 + ncol0 + nt*16 + l15]    = a0[r] + bb;
          augl[(16+q*4+r)*256 + ncol0 + nt*16 + l15] = a1[r] + bb;
        }
      });
    __syncthreads();
  }

  // ================= Sinkhorn + payments: wave w owns elements w*16..w*16+15 ==
  // Lane owns 4 columns (4c..4c+3) of element eL = w*16 + (l>>2).
  const int c = l & 3;
  const float Ssc = 14.426950408889634f; // (1/EPS)/ln2 : logits in exp2 units
  const float cmask = (c == 3) ? 1.0f : 0.0f;
  const int eL = w*16 + (l >> 2);
  const long e = rb + eL;

  floatx2 Kp[4][8];   // owned columns, rows (2k, 2k+1)
  floatx2 KPp[8];     // pad column 16 (lane 3 only; zero elsewhere), row-pairs

  const float* ap = (const float*)S + eL*256 + 4*c;
#pragma unroll
  for (int k=0;k<8;++k){
    float4 va = *(const float4*)(ap + (2*k  )*16);
    float4 vb = *(const float4*)(ap + (2*k+1)*16);
    Kp[0][k] = (floatx2){va.x*Ssc, vb.x*Ssc};
    Kp[1][k] = (floatx2){va.y*Ssc, vb.y*Ssc};
    Kp[2][k] = (floatx2){va.z*Ssc, vb.z*Ssc};
    Kp[3][k] = (floatx2){va.w*Ssc, vb.w*Ssc};
  }

  // max-subtract + exponentiate (row-wise, across the 4 lanes + pad col 0)
#pragma unroll
  for (int k=0;k<8;++k){
    float m0 = fmaxf(fmaxf(Kp[0][k].x,Kp[1][k].x), fmaxf(Kp[2][k].x,Kp[3][k].x));
    m0 = qmax2(fmaxf(m0, 0.0f));
    float m1 = fmaxf(fmaxf(Kp[0][k].y,Kp[1][k].y), fmaxf(Kp[2][k].y,Kp[3][k].y));
    m1 = qmax2(fmaxf(m1, 0.0f));
    Kp[0][k] = (floatx2){exp2_f(Kp[0][k].x-m0), exp2_f(Kp[0][k].y-m1)};
    Kp[1][k] = (floatx2){exp2_f(Kp[1][k].x-m0), exp2_f(Kp[1][k].y-m1)};
    Kp[2][k] = (floatx2){exp2_f(Kp[2][k].x-m0), exp2_f(Kp[2][k].y-m1)};
    Kp[3][k] = (floatx2){exp2_f(Kp[3][k].x-m0), exp2_f(Kp[3][k].y-m1)};
    KPp[k]   = (floatx2){cmask*exp2_f(-m0), cmask*exp2_f(-m1)};
  }
  // row 16: logits all 0, row max = 0 -> K entries exactly 1 (pad col: cmask)

  float vj0=1.f, vj1=1.f, vj2=1.f, vj3=1.f;
  float v16 = cmask;
  floatx2 u2[8];
  float u16;

  for (int r=0;r<40;++r){
    floatx2 b0=(floatx2){vj0,vj0}, b1=(floatx2){vj1,vj1};
    floatx2 b2=(floatx2){vj2,vj2}, b3=(floatx2){vj3,vj3};
    floatx2 b16=(floatx2){v16,v16};
    // ---- row normalization: u_i = 1 / sum_j K_ij v_j ----
#pragma unroll
    for (int k=0;k<8;++k){
      floatx2 pp = pk_mul2(Kp[0][k], b0);
      pp = pk_fma2(Kp[1][k], b1, pp);
      pp = pk_fma2(Kp[2][k], b2, pp);
      pp = pk_fma2(Kp[3][k], b3, pp);
      pp = pk_fma2(KPp[k], b16, pp);
      float px = qadd2(pp.x);
      float py = qadd2(pp.y);
      u2[k] = (floatx2){rcp_f(px), rcp_f(py)};
    }
    {
      // row 16: K == 1 across real cols, cmask on pad col; a_16 = I = 16
      float p16 = (vj0+vj1) + (vj2+vj3) + cmask*v16;
      p16 = qadd2(p16);
      u16 = 16.0f * rcp_f(p16);
    }
    // ---- column normalization: v_j = 1 / sum_i K_ij u_i ----
    floatx2 t0p = pk_mul2(Kp[0][0], u2[0]);
    floatx2 t1p = pk_mul2(Kp[1][0], u2[0]);
    floatx2 t2p = pk_mul2(Kp[2][0], u2[0]);
    floatx2 t3p = pk_mul2(Kp[3][0], u2[0]);
    floatx2 tPp = pk_mul2(KPp[0],   u2[0]);
#pragma unroll
    for (int k=1;k<8;++k){
      t0p = pk_fma2(Kp[0][k], u2[k], t0p);
      t1p = pk_fma2(Kp[1][k], u2[k], t1p);
      t2p = pk_fma2(Kp[2][k], u2[k], t2p);
      t3p = pk_fma2(Kp[3][k], u2[k], t3p);
      tPp = pk_fma2(KPp[k],   u2[k], tPp);
    }
    float t0 = t0p.x + t0p.y + u16;        // row-16 K == 1
    float t1 = t1p.x + t1p.y + u16;
    float t2 = t2p.x + t2p.y + u16;
    float t3 = t3p.x + t3p.y + u16;
    float t16 = tPp.x + tPp.y + cmask*u16;
    vj0 = rcp_f(t0); vj1 = rcp_f(t1); vj2 = rcp_f(t2); vj3 = rcp_f(t3);
    v16 = cmask * 16.0f * rcp_f(t16 + 1e-30f + (1.0f - cmask));  // b_16 = A = 16; NaN-guard off-lane
  }

  // ---- allocs = u_i K_ij v_j (write) + payments dot fused (reuse w) ----
  float* op = out + e*256 + 4*c;
  const float* bpx = X + e*256 + 4*c;
  float pv0=0.f, pv1=0.f, pv2=0.f, pv3=0.f;
#pragma unroll
  for (int k=0;k<8;++k){
#pragma unroll
    for (int h=0;h<2;++h){
      const int i = 2*k + h;
      const float uu = h ? u2[k].y : u2[k].x;
      const float K0 = h ? Kp[0][k].y : Kp[0][k].x;
      const float K1 = h ? Kp[1][k].y : Kp[1][k].x;
      const float K2 = h ? Kp[2][k].y : Kp[2][k].x;
      const float K3 = h ? Kp[3][k].y : Kp[3][k].x;
      float4 wv;
      wv.x = uu*K0*vj0;
      wv.y = uu*K1*vj1;
      wv.z = uu*K2*vj2;
      wv.w = uu*K3*vj3;
      *(float4*)(op + i*16) = wv;
      float4 bb = *(const float4*)(bpx + i*16);
      float s = wv.x*bb.x + wv.y*bb.y + wv.z*bb.z + wv.w*bb.w;
      s = qadd2(s);
      if ((i>>2) == c){
        const int rr = i & 3;
        if      (rr==0) pv0 = s;
        else if (rr==1) pv1 = s;
        else if (rr==2) pv2 = s;
        else            pv3 = s;
      }
    }
  }
  const float4 fr = *(const float4*)(frac_l + eL*16 + 4*c);
  float4 pvv;
  pvv.x = pv0*fr.x; pvv.y = pv1*fr.y; pvv.z = pv2*fr.z; pvv.w = pv3*fr.w;
  *(float4*)(out + (size_t)NB*256 + e*16 + 4*c) = pvv;
}

// ================= launch =================
extern "C" void kernel_launch(void* const* d_in, const int* in_sizes, int n_in,
                              void* d_out, int out_size, void* d_ws, size_t ws_size,
                              hipStream_t stream)
{
  const float* bids = (const float*)d_in[0];
  const float* aw0 = (const float*)d_in[1];  const float* ab0 = (const float*)d_in[2];
  const float* aw1 = (const float*)d_in[3];  const float* ab1 = (const float*)d_in[4];
  const float* aw2 = (const float*)d_in[5];  const float* ab2 = (const float*)d_in[6];
  const float* aw3 = (const float*)d_in[7];  const float* ab3 = (const float*)d_in[8];
  const float* pw0 = (const float*)d_in[9];  const float* pb0 = (const float*)d_in[10];
  const float* pw1 = (const float*)d_in[11]; const float* pb1 = (const float*)d_in[12];
  const float* pw2 = (const float*)d_in[13]; const float* pb2 = (const float*)d_in[14];
  const float* pw3 = (const float*)d_in[15]; const float* pb3 = (const float*)d_in[16];

  _Float16* WT = (_Float16*)d_ws;

  // nshift = log2(N) where W is K x N (row-major src); dst is N x K (transposed)
  PrepJobs js;
  js.j[0] = { aw0, WT+O_AW0H, nullptr,    7, 32768 };  // 256x128
  js.j[1] = { aw1, WT+O_AW1H, WT+O_AW1L,  7, 16384 };  // 128x128
  js.j[2] = { aw2, WT+O_AW2H, WT+O_AW2L,  7, 16384 };  // 128x128
  js.j[3] = { aw3, WT+O_AW3H, WT+O_AW3L,  8, 32768 };  // 128x256
  js.j[4] = { pw0, WT+O_PW0H, nullptr,    7, 32768 };  // 256x128
  js.j[5] = { pw1, WT+O_PW1H, nullptr,    7, 16384 };  // 128x128
  js.j[6] = { pw2, WT+O_PW2H, nullptr,    7, 16384 };  // 128x128
  js.j[7] = { pw3, WT+O_PW3H, nullptr,    4, 2048  };  // 128x16

  prep_kernel<<<dim3(128,8), 256, 0, stream>>>(js);
  fused_kernel<<<dim3(NB/32), 128, 0, stream>>>(bids, WT, ab0,ab1,ab2,ab3,
                                                pb0,pb1,pb2,pb3, (float*)d_out);
}

// Round 8
// 194.570 us; speedup vs baseline: 1.3290x; 1.0212x over previous
//
#include <hip/hip_runtime.h>

#define NB 32768

typedef _Float16 half8 __attribute__((ext_vector_type(8)));
typedef float floatx4 __attribute__((ext_vector_type(4)));
typedef float floatx2 __attribute__((ext_vector_type(2)));

#define MFMA16(a,b,c) __builtin_amdgcn_mfma_f32_16x16x32_f16(a,b,c,0,0,0)

// ---------- fast math ----------
__device__ __forceinline__ float rcp_f(float x){ return __builtin_amdgcn_rcpf(x); }
__device__ __forceinline__ float exp2_f(float x){ return __builtin_amdgcn_exp2f(x); }
__device__ __forceinline__ float tanh_f(float x){
  float e = exp2_f(x * 2.8853900817779268f);     // e^(2x)
  return (e - 1.0f) * rcp_f(e + 1.0f);
}
__device__ __forceinline__ float sigmoid_f(float x){
  return rcp_f(1.0f + exp2_f(-1.4426950408889634f * x));
}

// packed f32 math (VOP3P)
__device__ __forceinline__ floatx2 pk_mul2(floatx2 a, floatx2 b){
  floatx2 d; asm("v_pk_mul_f32 %0, %1, %2" : "=v"(d) : "v"(a), "v"(b)); return d;
}
__device__ __forceinline__ floatx2 pk_fma2(floatx2 a, floatx2 b, floatx2 c){
  floatx2 d; asm("v_pk_fma_f32 %0, %1, %2, %3" : "=v"(d) : "v"(a), "v"(b), "v"(c)); return d;
}

// DPP quad butterflies: xor1 = quad_perm[1,0,3,2]=0xB1, xor2 = [2,3,0,1]=0x4E
template<int CTRL>
__device__ __forceinline__ float dpp_qp(float x){
  return __builtin_bit_cast(float, __builtin_amdgcn_update_dpp(0, __builtin_bit_cast(int,x), CTRL, 0xF, 0xF, true));
}
__device__ __forceinline__ float qadd2(float x){
  x += dpp_qp<0xB1>(x);
  x += dpp_qp<0x4E>(x);
  return x;
}
__device__ __forceinline__ float qmax2(float x){
  x = fmaxf(x, dpp_qp<0xB1>(x));
  x = fmaxf(x, dpp_qp<0x4E>(x));
  return x;
}

// ---------- f16 weight region offsets (in _Float16 units), lives in d_ws ----------
constexpr int O_AW0H = 0;        // 256x128
constexpr int O_AW1H = 32768;    // 128x128
constexpr int O_AW2H = 49152;
constexpr int O_AW3H = 65536;    // 128x256
constexpr int O_PW0H = 98304;
constexpr int O_PW1H = 131072;
constexpr int O_PW2H = 147456;
constexpr int O_PW3H = 163840;   // 128x16
constexpr int O_AW1L = 165888;
constexpr int O_AW2L = 182272;
constexpr int O_AW3L = 198656;

// ---------- weight prep: transpose + split f32 -> f16 hi/lo ----------
struct PrepJob { const float* src; _Float16* h; _Float16* l; int nshift; int total; };
struct PrepJobs { PrepJob j[8]; };

__global__ void prep_kernel(PrepJobs js){
  const PrepJob jb = js.j[blockIdx.y];
  const int idx = blockIdx.x*256 + threadIdx.x;
  if (idx >= jb.total) return;
  const int N = 1 << jb.nshift;
  const int n = idx & (N-1);           // fastest-varying -> coalesced src read
  const int k = idx >> jb.nshift;
  const int K = jb.total >> jb.nshift;
  float w = jb.src[idx];               // src[k*N + n] == src[idx]
  _Float16 h = (_Float16)w;
  jb.h[(long)n*K + k] = h;
  if (jb.l) jb.l[(long)n*K + k] = (_Float16)(w - (float)h);
}

// ---------- LDS activation layout: UNPACKED hi/lo _Float16 arrays ----------
// Per array: [32 rows][17 chunks][8 f16]  (pad chunk breaks 256B bank period)
// chunk c of row = cols c*8..c*8+7. Frag (ks,q) = chunk ks*4+q. Direct b128 reads.
__device__ __forceinline__ half8 ld_frag(const _Float16* __restrict__ a, int row, int ks, int q){
  return *(const half8*)(a + (row*17 + ks*4 + q)*8);
}
__device__ __forceinline__ void st_hl(_Float16* __restrict__ ah, _Float16* __restrict__ al,
                                      int row, int col, float v){
  const int o = (row*17 + (col>>3))*8 + (col&7);
  _Float16 h = (_Float16)v;
  ah[o] = h;
  al[o] = (_Float16)(v - (float)h);
}
__device__ __forceinline__ void st_h(_Float16* __restrict__ ah, int row, int col, float v){
  ah[(row*17 + (col>>3))*8 + (col&7)] = (_Float16)v;
}

// ---------- load one weight tile's fragments into a register stage ----------
template<int KS, bool LO>
__device__ __forceinline__ void load_tile(
    const _Float16* __restrict__ Wh, const _Float16* __restrict__ Wl,
    int K, int nt, int l15, int q, half8* bh, half8* bl)
{
  const _Float16* bp = Wh + (nt*16 + l15)*K + q*8;
#pragma unroll
  for (int ks=0; ks<KS; ++ks) bh[ks] = *(const half8*)(bp + ks*32);
  if constexpr (LO){
    const _Float16* blp = Wl + (nt*16 + l15)*K + q*8;
#pragma unroll
    for (int ks=0; ks<KS; ++ks) bl[ks] = *(const half8*)(blp + ks*32);
  }
}

// ---------- DUAL m-tile MFMA stream over n-tiles nt0..nt0+NT-1 (r7-proven) ----------
template<int KS, int PASSES, int NT, int RING, typename EPI>
__device__ __forceinline__ void mfma_stream2(
    const half8* Ah0, const half8* Al0,
    const half8* Ah1, const half8* Al1,
    const _Float16* __restrict__ Wh, const _Float16* __restrict__ Wl,
    int K, int nt0, int l15, int q, EPI&& epi)
{
  half8 Bh[RING][KS], Bl[RING][KS];
  load_tile<KS,PASSES==3>(Wh, Wl, K, nt0, l15, q, Bh[0], Bl[0]);
  if constexpr (RING > 2){
    if constexpr (NT > 1)
      load_tile<KS,PASSES==3>(Wh, Wl, K, nt0+1, l15, q, Bh[1], Bl[1]);
  }
#pragma unroll
  for (int nt=0; nt<NT; ++nt){
    constexpr int PD = RING - 1;
    if (nt+PD < NT)
      load_tile<KS,PASSES==3>(Wh, Wl, K, nt0+nt+PD, l15, q, Bh[(nt+PD)%RING], Bl[(nt+PD)%RING]);
    floatx4 a0e=(floatx4)0.0f, a0o=(floatx4)0.0f;
    floatx4 a1e=(floatx4)0.0f, a1o=(floatx4)0.0f;
#pragma unroll
    for (int ks=0; ks<KS; ++ks){
      const half8 bh = Bh[nt%RING][ks];
      floatx4& c0 = (ks & 1) ? a0o : a0e;
      floatx4& c1 = (ks & 1) ? a1o : a1e;
      c0 = MFMA16(Ah0[ks], bh, c0);
      c1 = MFMA16(Ah1[ks], bh, c1);
      if constexpr (PASSES == 3){
        const half8 bl = Bl[nt%RING][ks];
        c0 = MFMA16(Al0[ks], bh, c0);
        c0 = MFMA16(Ah0[ks], bl, c0);
        c1 = MFMA16(Al1[ks], bh, c1);
        c1 = MFMA16(Ah1[ks], bl, c1);
      }
    }
    floatx4 acc0, acc1;
#pragma unroll
    for (int r=0; r<4; ++r){ acc0[r] = a0e[r] + a0o[r]; acc1[r] = a1e[r] + a1o[r]; }
    epi(nt0+nt, acc0, acc1);
  }
}

// ---------- INTERLEAVED hidden stage: a-net (3-pass) + p-net (1-pass) in one
// scheduling region. Pre-read all frags (in-place update) -> barrier ->
// per-slot {prefetch a+p, 24 a-MFMA, 8 p-MFMA, both epilogues} -> barrier.
__device__ __forceinline__ void stage_dual(
    _Float16* __restrict__ aAh, _Float16* __restrict__ aAl, _Float16* __restrict__ aPh,
    const _Float16* __restrict__ Wah, const _Float16* __restrict__ Wal,
    const float* __restrict__ ba,
    const _Float16* __restrict__ Wph, const float* __restrict__ bpp,
    int nt0, int l15, int q)
{
  half8 Fa0h[4], Fa0l[4], Fa1h[4], Fa1l[4], Fp0[4], Fp1[4];
#pragma unroll
  for (int ks=0; ks<4; ++ks){
    Fa0h[ks] = ld_frag(aAh, l15,      ks, q);
    Fa0l[ks] = ld_frag(aAl, l15,      ks, q);
    Fa1h[ks] = ld_frag(aAh, 16 + l15, ks, q);
    Fa1l[ks] = ld_frag(aAl, 16 + l15, ks, q);
    Fp0[ks]  = ld_frag(aPh, l15,      ks, q);
    Fp1[ks]  = ld_frag(aPh, 16 + l15, ks, q);
  }
  __syncthreads();

  half8 Bah[2][4], Bal[2][4], Bph[2][4];
  load_tile<4,true >(Wah, Wal, 128, nt0, l15, q, Bah[0], Bal[0]);
  load_tile<4,false>(Wph, Wph, 128, nt0, l15, q, Bph[0], Bph[0]);
#pragma unroll
  for (int nt=0; nt<4; ++nt){
    if (nt+1 < 4){
      load_tile<4,true >(Wah, Wal, 128, nt0+nt+1, l15, q, Bah[(nt+1)&1], Bal[(nt+1)&1]);
      load_tile<4,false>(Wph, Wph, 128, nt0+nt+1, l15, q, Bph[(nt+1)&1], Bph[(nt+1)&1]);
    }
    floatx4 a0e=(floatx4)0.0f, a0o=(floatx4)0.0f;
    floatx4 a1e=(floatx4)0.0f, a1o=(floatx4)0.0f;
    floatx4 p0 =(floatx4)0.0f, p1 =(floatx4)0.0f;
#pragma unroll
    for (int ks=0; ks<4; ++ks){
      const half8 bh = Bah[nt&1][ks], bl = Bal[nt&1][ks];
      floatx4& c0 = (ks & 1) ? a0o : a0e;
      floatx4& c1 = (ks & 1) ? a1o : a1e;
      c0 = MFMA16(Fa0h[ks], bh, c0);
      c1 = MFMA16(Fa1h[ks], bh, c1);
      c0 = MFMA16(Fa0l[ks], bh, c0);
      c0 = MFMA16(Fa0h[ks], bl, c0);
      c1 = MFMA16(Fa1l[ks], bh, c1);
      c1 = MFMA16(Fa1h[ks], bl, c1);
    }
#pragma unroll
    for (int ks=0; ks<4; ++ks){
      p0 = MFMA16(Fp0[ks], Bph[nt&1][ks], p0);
      p1 = MFMA16(Fp1[ks], Bph[nt&1][ks], p1);
    }
    const int ntg = nt0 + nt;
    const float bba = ba [ntg*16 + l15];
    const float bbp = bpp[ntg*16 + l15];
#pragma unroll
    for (int r=0; r<4; ++r){
      st_hl(aAh, aAl,      q*4 + r, ntg*16 + l15, tanh_f(a0e[r] + a0o[r] + bba));
      st_hl(aAh, aAl, 16 + q*4 + r, ntg*16 + l15, tanh_f(a1e[r] + a1o[r] + bba));
      st_h (aPh,           q*4 + r, ntg*16 + l15, tanh_f(p0[r] + bbp));
      st_h (aPh,      16 + q*4 + r, ntg*16 + l15, tanh_f(p1[r] + bbp));
    }
  }
  __syncthreads();
}

// ================= Fused kernel: MLPs + Sinkhorn + payments =================
// 128 threads = 2 waves, 32 rows/block (2 m-tiles), N-split (wave w owns cols
// w*64..w*64+63). Unpacked hi/lo act arrays (pad-swizzled) — no bit-unpack VALU.
// LDS bytes: [0,8704) act_a_h, [8704,17408) act_a_l, [17408,26112) act_p_h,
//            aug f32 overlay = [0,32768) after final-stage pre-reads,
//            [32768,34816) frac f32.  34816 B -> 4 blocks/CU (8 waves/CU).
__global__ __launch_bounds__(128, 2) void fused_kernel(
  const float* __restrict__ X, const _Float16* __restrict__ WT,
  const float* __restrict__ ab0, const float* __restrict__ ab1,
  const float* __restrict__ ab2, const float* __restrict__ ab3,
  const float* __restrict__ pb0, const float* __restrict__ pb1,
  const float* __restrict__ pb2, const float* __restrict__ pb3,
  float* __restrict__ out)
{
  __shared__ unsigned int S[8704];   // 34816 B
  _Float16* act_a_h = (_Float16*)S;
  _Float16* act_a_l = (_Float16*)S + 4352;
  _Float16* act_p_h = (_Float16*)S + 8704;
  float* frac_l = (float*)(S + 8192);
  const int t = threadIdx.x;
  const int w = t >> 6;                      // wave id 0/1
  const int l = t & 63, q = l>>4, l15 = l&15;
  const int nt0 = w*4;                       // this wave's n-tile base
  const long rb = (long)blockIdx.x * 32;

  // ---- L1 of both nets: X frags for both m-tiles (K=256), own 4 n-tiles ----
  {
    half8 Xf0[8], Xf1[8];
#pragma unroll
    for (int mt=0; mt<2; ++mt){
      float4 xa[8], xb[8];
#pragma unroll
      for (int ks=0; ks<8; ++ks){
        const float* xp = X + (rb + mt*16 + l15)*256 + ks*32 + q*8;
        xa[ks] = *(const float4*)(xp);
        xb[ks] = *(const float4*)(xp + 4);
      }
      half8* Xf = mt ? Xf1 : Xf0;
#pragma unroll
      for (int ks=0; ks<8; ++ks){
        half8 h;
        h[0]=(_Float16)xa[ks].x; h[1]=(_Float16)xa[ks].y; h[2]=(_Float16)xa[ks].z; h[3]=(_Float16)xa[ks].w;
        h[4]=(_Float16)xb[ks].x; h[5]=(_Float16)xb[ks].y; h[6]=(_Float16)xb[ks].z; h[7]=(_Float16)xb[ks].w;
        Xf[ks] = h;
      }
    }
    mfma_stream2<8,1,4,2>(Xf0, Xf0, Xf1, Xf1, WT+O_AW0H, WT+O_AW0H, 256, nt0, l15, q,
      [&](int ntg, floatx4 a0, floatx4 a1){
        float bb = ab0[ntg*16 + l15];
#pragma unroll
        for (int r=0; r<4; ++r){
          st_hl(act_a_h, act_a_l,      q*4 + r, ntg*16 + l15, tanh_f(a0[r] + bb));
          st_hl(act_a_h, act_a_l, 16 + q*4 + r, ntg*16 + l15, tanh_f(a1[r] + bb));
        }
      });
    mfma_stream2<8,1,4,2>(Xf0, Xf0, Xf1, Xf1, WT+O_PW0H, WT+O_PW0H, 256, nt0, l15, q,
      [&](int ntg, floatx4 a0, floatx4 a1){
        float bb = pb0[ntg*16 + l15];
#pragma unroll
        for (int r=0; r<4; ++r){
          st_h(act_p_h,      q*4 + r, ntg*16 + l15, tanh_f(a0[r] + bb));
          st_h(act_p_h, 16 + q*4 + r, ntg*16 + l15, tanh_f(a1[r] + bb));
        }
      });
  }
  __syncthreads();

  // ---- hidden stages, interleaved a/p ----
  stage_dual(act_a_h, act_a_l, act_p_h, WT+O_AW1H, WT+O_AW1L, ab1, WT+O_PW1H, pb1, nt0, l15, q);
  stage_dual(act_a_h, act_a_l, act_p_h, WT+O_AW2H, WT+O_AW2L, ab2, WT+O_PW2H, pb2, nt0, l15, q);

  // ---- final stage: pre-read frags, barrier; pL4 (wave0) + aL4 half hf=w ----
  {
    half8 Fa0h[4], Fa0l[4], Fa1h[4], Fa1l[4], Fp0[4], Fp1[4];
#pragma unroll
    for (int ks=0; ks<4; ++ks){
      Fa0h[ks] = ld_frag(act_a_h, l15,      ks, q);
      Fa0l[ks] = ld_frag(act_a_l, l15,      ks, q);
      Fa1h[ks] = ld_frag(act_a_h, 16 + l15, ks, q);
      Fa1l[ks] = ld_frag(act_a_l, 16 + l15, ks, q);
    }
    if (w == 0){
#pragma unroll
      for (int ks=0; ks<4; ++ks){
        Fp0[ks] = ld_frag(act_p_h, l15,      ks, q);
        Fp1[ks] = ld_frag(act_p_h, 16 + l15, ks, q);
      }
    }
    __syncthreads();
    if (w == 0){
      mfma_stream2<4,1,1,2>(Fp0, Fp0, Fp1, Fp1, WT+O_PW3H, WT+O_PW3H, 128, 0, l15, q,
        [&](int, floatx4 a0, floatx4 a1){
          float bb = pb3[l15];
#pragma unroll
          for (int r=0; r<4; ++r){
            frac_l[(q*4+r)*16 + l15]    = sigmoid_f(a0[r] + bb);
            frac_l[(16+q*4+r)*16 + l15] = sigmoid_f(a1[r] + bb);
          }
        });
    }
    // aug half hf = w (cols w*128..w*128+127) overlays act arrays (reads done)
    float* augl = (float*)S;
    const int ncol0 = w*128;
    mfma_stream2<4,3,8,2>(Fa0h, Fa0l, Fa1h, Fa1l,
                          WT+O_AW3H + w*128*128, WT+O_AW3L + w*128*128,
                          128, 0, l15, q,
      [&](int nt, floatx4 a0, floatx4 a1){
        float bb = ab3[ncol0 + nt*16 + l15];
#pragma unroll
        for (int r=0; r<4; ++r){
          augl[(q*4+r)*256 + ncol0 + nt*16 + l15]    = a0[r] + bb;
          augl[(16+q*4+r)*256 + ncol0 + nt*16 + l15] = a1[r] + bb;
        }
      });
    __syncthreads();
  }

  // ================= Sinkhorn + payments: wave w owns elements w*16..w*16+15 ==
  const int c = l & 3;
  const float Ssc = 14.426950408889634f; // (1/EPS)/ln2 : logits in exp2 units
  const float cmask = (c == 3) ? 1.0f : 0.0f;
  const int eL = w*16 + (l >> 2);
  const long e = rb + eL;

  floatx2 Kp[4][8];   // owned columns, rows (2k, 2k+1)
  floatx2 KPp[8];     // pad column 16 (lane 3 only; zero elsewhere), row-pairs

  const float* ap = (const float*)S + eL*256 + 4*c;
#pragma unroll
  for (int k=0;k<8;++k){
    float4 va = *(const float4*)(ap + (2*k  )*16);
    float4 vb = *(const float4*)(ap + (2*k+1)*16);
    Kp[0][k] = (floatx2){va.x*Ssc, vb.x*Ssc};
    Kp[1][k] = (floatx2){va.y*Ssc, vb.y*Ssc};
    Kp[2][k] = (floatx2){va.z*Ssc, vb.z*Ssc};
    Kp[3][k] = (floatx2){va.w*Ssc, vb.w*Ssc};
  }

  // max-subtract + exponentiate (row-wise, across the 4 lanes + pad col 0)
#pragma unroll
  for (int k=0;k<8;++k){
    float m0 = fmaxf(fmaxf(Kp[0][k].x,Kp[1][k].x), fmaxf(Kp[2][k].x,Kp[3][k].x));
    m0 = qmax2(fmaxf(m0, 0.0f));
    float m1 = fmaxf(fmaxf(Kp[0][k].y,Kp[1][k].y), fmaxf(Kp[2][k].y,Kp[3][k].y));
    m1 = qmax2(fmaxf(m1, 0.0f));
    Kp[0][k] = (floatx2){exp2_f(Kp[0][k].x-m0), exp2_f(Kp[0][k].y-m1)};
    Kp[1][k] = (floatx2){exp2_f(Kp[1][k].x-m0), exp2_f(Kp[1][k].y-m1)};
    Kp[2][k] = (floatx2){exp2_f(Kp[2][k].x-m0), exp2_f(Kp[2][k].y-m1)};
    Kp[3][k] = (floatx2){exp2_f(Kp[3][k].x-m0), exp2_f(Kp[3][k].y-m1)};
    KPp[k]   = (floatx2){cmask*exp2_f(-m0), cmask*exp2_f(-m1)};
  }
  // row 16: logits all 0, row max = 0 -> K entries exactly 1 (pad col: cmask)

  float vj0=1.f, vj1=1.f, vj2=1.f, vj3=1.f;
  float v16 = cmask;
  floatx2 u2[8];
  float u16;

  for (int r=0;r<40;++r){
    floatx2 b0=(floatx2){vj0,vj0}, b1=(floatx2){vj1,vj1};
    floatx2 b2=(floatx2){vj2,vj2}, b3=(floatx2){vj3,vj3};
    floatx2 b16=(floatx2){v16,v16};
    // ---- row normalization: u_i = 1 / sum_j K_ij v_j ----
#pragma unroll
    for (int k=0;k<8;++k){
      floatx2 pp = pk_mul2(Kp[0][k], b0);
      pp = pk_fma2(Kp[1][k], b1, pp);
      pp = pk_fma2(Kp[2][k], b2, pp);
      pp = pk_fma2(Kp[3][k], b3, pp);
      pp = pk_fma2(KPp[k], b16, pp);
      float px = qadd2(pp.x);
      float py = qadd2(pp.y);
      u2[k] = (floatx2){rcp_f(px), rcp_f(py)};
    }
    {
      // row 16: K == 1 across real cols, cmask on pad col; a_16 = I = 16
      float p16 = (vj0+vj1) + (vj2+vj3) + cmask*v16;
      p16 = qadd2(p16);
      u16 = 16.0f * rcp_f(p16);
    }
    // ---- column normalization: v_j = 1 / sum_i K_ij u_i ----
    floatx2 t0p = pk_mul2(Kp[0][0], u2[0]);
    floatx2 t1p = pk_mul2(Kp[1][0], u2[0]);
    floatx2 t2p = pk_mul2(Kp[2][0], u2[0]);
    floatx2 t3p = pk_mul2(Kp[3][0], u2[0]);
    floatx2 tPp = pk_mul2(KPp[0],   u2[0]);
#pragma unroll
    for (int k=1;k<8;++k){
      t0p = pk_fma2(Kp[0][k], u2[k], t0p);
      t1p = pk_fma2(Kp[1][k], u2[k], t1p);
      t2p = pk_fma2(Kp[2][k], u2[k], t2p);
      t3p = pk_fma2(Kp[3][k], u2[k], t3p);
      tPp = pk_fma2(KPp[k],   u2[k], tPp);
    }
    float t0 = t0p.x + t0p.y + u16;        // row-16 K == 1
    float t1 = t1p.x + t1p.y + u16;
    float t2 = t2p.x + t2p.y + u16;
    float t3 = t3p.x + t3p.y + u16;
    float t16 = tPp.x + tPp.y + cmask*u16;
    vj0 = rcp_f(t0); vj1 = rcp_f(t1); vj2 = rcp_f(t2); vj3 = rcp_f(t3);
    v16 = cmask * 16.0f * rcp_f(t16 + 1e-30f + (1.0f - cmask));  // b_16 = A = 16; NaN-guard off-lane
  }

  // ---- allocs = u_i K_ij v_j (write) + payments dot fused (reuse w) ----
  float* op = out + e*256 + 4*c;
  const float* bpx = X + e*256 + 4*c;
  float pv0=0.f, pv1=0.f, pv2=0.f, pv3=0.f;
#pragma unroll
  for (int k=0;k<8;++k){
#pragma unroll
    for (int h=0;h<2;++h){
      const int i = 2*k + h;
      const float uu = h ? u2[k].y : u2[k].x;
      const float K0 = h ? Kp[0][k].y : Kp[0][k].x;
      const float K1 = h ? Kp[1][k].y : Kp[1][k].x;
      const float K2 = h ? Kp[2][k].y : Kp[2][k].x;
      const float K3 = h ? Kp[3][k].y : Kp[3][k].x;
      float4 wv;
      wv.x = uu*K0*vj0;
      wv.y = uu*K1*vj1;
      wv.z = uu*K2*vj2;
      wv.w = uu*K3*vj3;
      *(float4*)(op + i*16) = wv;
      float4 bb = *(const float4*)(bpx + i*16);
      float s = wv.x*bb.x + wv.y*bb.y + wv.z*bb.z + wv.w*bb.w;
      s = qadd2(s);
      if ((i>>2) == c){
        const int rr = i & 3;
        if      (rr==0) pv0 = s;
        else if (rr==1) pv1 = s;
        else if (rr==2) pv2 = s;
        else            pv3 = s;
      }
    }
  }
  const float4 fr = *(const float4*)(frac_l + eL*16 + 4*c);
  float4 pvv;
  pvv.x = pv0*fr.x; pvv.y = pv1*fr.y; pvv.z = pv2*fr.z; pvv.w = pv3*fr.w;
  *(float4*)(out + (size_t)NB*256 + e*16 + 4*c) = pvv;
}

// ================= launch =================
extern "C" void kernel_launch(void* const* d_in, const int* in_sizes, int n_in,
                              void* d_out, int out_size, void* d_ws, size_t ws_size,
                              hipStream_t stream)
{
  const float* bids = (const float*)d_in[0];
  const float* aw0 = (const float*)d_in[1];  const float* ab0 = (const float*)d_in[2];
  const float* aw1 = (const float*)d_in[3];  const float* ab1 = (const float*)d_in[4];
  const float* aw2 = (const float*)d_in[5];  const float* ab2 = (const float*)d_in[6];
  const float* aw3 = (const float*)d_in[7];  const float* ab3 = (const float*)d_in[8];
  const float* pw0 = (const float*)d_in[9];  const float* pb0 = (const float*)d_in[10];
  const float* pw1 = (const float*)d_in[11]; const float* pb1 = (const float*)d_in[12];
  const float* pw2 = (const float*)d_in[13]; const float* pb2 = (const float*)d_in[14];
  const float* pw3 = (const float*)d_in[15]; const float* pb3 = (const float*)d_in[16];

  _Float16* WT = (_Float16*)d_ws;

  // nshift = log2(N) where W is K x N (row-major src); dst is N x K (transposed)
  PrepJobs js;
  js.j[0] = { aw0, WT+O_AW0H, nullptr,    7, 32768 };  // 256x128
  js.j[1] = { aw1, WT+O_AW1H, WT+O_AW1L,  7, 16384 };  // 128x128
  js.j[2] = { aw2, WT+O_AW2H, WT+O_AW2L,  7, 16384 };  // 128x128
  js.j[3] = { aw3, WT+O_AW3H, WT+O_AW3L,  8, 32768 };  // 128x256
  js.j[4] = { pw0, WT+O_PW0H, nullptr,    7, 32768 };  // 256x128
  js.j[5] = { pw1, WT+O_PW1H, nullptr,    7, 16384 };  // 128x128
  js.j[6] = { pw2, WT+O_PW2H, nullptr,    7, 16384 };  // 128x128
  js.j[7] = { pw3, WT+O_PW3H, nullptr,    4, 2048  };  // 128x16

  prep_kernel<<<dim3(128,8), 256, 0, stream>>>(js);
  fused_kernel<<<dim3(NB/32), 128, 0, stream>>>(bids, WT, ab0,ab1,ab2,ab3,
                                                pb0,pb1,pb2,pb3, (float*)d_out);
}

// Round 9
// 184.932 us; speedup vs baseline: 1.3983x; 1.0521x over previous
//
#include <hip/hip_runtime.h>

#define NB 32768

typedef _Float16 half8 __attribute__((ext_vector_type(8)));
typedef float floatx4 __attribute__((ext_vector_type(4)));
typedef float floatx2 __attribute__((ext_vector_type(2)));
typedef unsigned int uint4v __attribute__((ext_vector_type(4)));

#define MFMA16(a,b,c) __builtin_amdgcn_mfma_f32_16x16x32_f16(a,b,c,0,0,0)

// ---------- fast math ----------
__device__ __forceinline__ float rcp_f(float x){ return __builtin_amdgcn_rcpf(x); }
__device__ __forceinline__ float exp2_f(float x){ return __builtin_amdgcn_exp2f(x); }
__device__ __forceinline__ float tanh_f(float x){
  float e = exp2_f(x * 2.8853900817779268f);     // e^(2x)
  return (e - 1.0f) * rcp_f(e + 1.0f);
}
__device__ __forceinline__ float sigmoid_f(float x){
  return rcp_f(1.0f + exp2_f(-1.4426950408889634f * x));
}

// packed f32 math (VOP3P)
__device__ __forceinline__ floatx2 pk_mul2(floatx2 a, floatx2 b){
  floatx2 d; asm("v_pk_mul_f32 %0, %1, %2" : "=v"(d) : "v"(a), "v"(b)); return d;
}
__device__ __forceinline__ floatx2 pk_fma2(floatx2 a, floatx2 b, floatx2 c){
  floatx2 d; asm("v_pk_fma_f32 %0, %1, %2, %3" : "=v"(d) : "v"(a), "v"(b), "v"(c)); return d;
}

// DPP quad butterflies: xor1 = quad_perm[1,0,3,2]=0xB1, xor2 = [2,3,0,1]=0x4E
template<int CTRL>
__device__ __forceinline__ float dpp_qp(float x){
  return __builtin_bit_cast(float, __builtin_amdgcn_update_dpp(0, __builtin_bit_cast(int,x), CTRL, 0xF, 0xF, true));
}
__device__ __forceinline__ float qadd2(float x){
  x += dpp_qp<0xB1>(x);
  x += dpp_qp<0x4E>(x);
  return x;
}
__device__ __forceinline__ float qmax2(float x){
  x = fmaxf(x, dpp_qp<0xB1>(x));
  x = fmaxf(x, dpp_qp<0x4E>(x));
  return x;
}

// ---------- f16 weight region offsets (in _Float16 units), lives in d_ws ----------
constexpr int O_AW0H = 0;        // 256x128
constexpr int O_AW1H = 32768;    // 128x128
constexpr int O_AW2H = 49152;
constexpr int O_AW3H = 65536;    // 128x256
constexpr int O_PW0H = 98304;
constexpr int O_PW1H = 131072;
constexpr int O_PW2H = 147456;
constexpr int O_PW3H = 163840;   // 128x16
constexpr int O_AW1L = 165888;
constexpr int O_AW2L = 182272;
constexpr int O_AW3L = 198656;

// ---------- weight prep: transpose + split f32 -> f16 hi/lo ----------
struct PrepJob { const float* src; _Float16* h; _Float16* l; int nshift; int total; };
struct PrepJobs { PrepJob j[8]; };

__global__ void prep_kernel(PrepJobs js){
  const PrepJob jb = js.j[blockIdx.y];
  const int idx = blockIdx.x*256 + threadIdx.x;
  if (idx >= jb.total) return;
  const int N = 1 << jb.nshift;
  const int n = idx & (N-1);           // fastest-varying -> coalesced src read
  const int k = idx >> jb.nshift;
  const int K = jb.total >> jb.nshift;
  float w = jb.src[idx];               // src[k*N + n] == src[idx]
  _Float16 h = (_Float16)w;
  jb.h[(long)n*K + k] = h;
  if (jb.l) jb.l[(long)n*K + k] = (_Float16)(w - (float)h);
}

// ---------- LDS activation layout: 64 rows x 128 cols of packed (hi|lo) u32 ----------
// 16B-chunk XOR swizzle by (row&7)
__device__ __forceinline__ int aaddr(int row, int col){
  int cc = (col >> 2) ^ (row & 7);
  return row*128 + (cc<<2) + (col & 3);
}

template<bool NEED_LO>
__device__ __forceinline__ void read_frag(const unsigned int* __restrict__ act,
    int row, int ks, int q, half8& ah, half8& al)
{
  const int s = row & 7;
  const int cc0 = ks*8 + q*2;
  uint4v c0 = *(const uint4v*)(act + row*128 + (((cc0  ) ^ s)<<2));
  uint4v c1 = *(const uint4v*)(act + row*128 + (((cc0+1) ^ s)<<2));
  uint4v h;
  h.x = (c0.x & 0xffffu) | (c0.y << 16);
  h.y = (c0.z & 0xffffu) | (c0.w << 16);
  h.z = (c1.x & 0xffffu) | (c1.y << 16);
  h.w = (c1.z & 0xffffu) | (c1.w << 16);
  ah = __builtin_bit_cast(half8, h);
  if constexpr (NEED_LO){
    uint4v g;
    g.x = (c0.x >> 16) | (c0.y & 0xffff0000u);
    g.y = (c0.z >> 16) | (c0.w & 0xffff0000u);
    g.z = (c1.x >> 16) | (c1.y & 0xffff0000u);
    g.w = (c1.z >> 16) | (c1.w & 0xffff0000u);
    al = __builtin_bit_cast(half8, g);
  }
}

__device__ __forceinline__ unsigned int pack_act(float v){
  _Float16 h = (_Float16)v;
  _Float16 lo = (_Float16)(v - (float)h);
  return (unsigned int)__builtin_bit_cast(unsigned short, h)
       | ((unsigned int)__builtin_bit_cast(unsigned short, lo) << 16);
}
__device__ __forceinline__ unsigned int pack_act_hi(float v){
  return (unsigned int)__builtin_bit_cast(unsigned short, (_Float16)v);
}

// ---------- load one weight tile's fragments into a register stage ----------
template<int KS, bool LO>
__device__ __forceinline__ void load_tile(
    const _Float16* __restrict__ Wh, const _Float16* __restrict__ Wl,
    int K, int nt, int l15, int q, half8* bh, half8* bl)
{
  const _Float16* bp = Wh + (nt*16 + l15)*K + q*8;
#pragma unroll
  for (int ks=0; ks<KS; ++ks) bh[ks] = *(const half8*)(bp + ks*32);
  if constexpr (LO){
    const _Float16* blp = Wl + (nt*16 + l15)*K + q*8;
#pragma unroll
    for (int ks=0; ks<KS; ++ks) bl[ks] = *(const half8*)(blp + ks*32);
  }
}

// ---------- QUAD m-tile MFMA stream over n-tiles nt0..nt0+NT-1 ----------
// Each loaded B-frag feeds 4 MFMAs (4 m-tiles = 4-way acc ILP). Ring prefetch.
template<int KS, int PASSES, int NT, int RING, typename EPI>
__device__ __forceinline__ void mfma_stream4(
    const half8 (&Ah)[4][KS], const half8 (&Al)[4][KS],
    const _Float16* __restrict__ Wh, const _Float16* __restrict__ Wl,
    int K, int nt0, int l15, int q, EPI&& epi)
{
  half8 Bh[RING][KS], Bl[RING][KS];
  load_tile<KS,PASSES==3>(Wh, Wl, K, nt0, l15, q, Bh[0], Bl[0]);
  if constexpr (RING > 2){
    if constexpr (NT > 1)
      load_tile<KS,PASSES==3>(Wh, Wl, K, nt0+1, l15, q, Bh[1], Bl[1]);
  }
#pragma unroll
  for (int nt=0; nt<NT; ++nt){
    constexpr int PD = RING - 1;
    if (nt+PD < NT)
      load_tile<KS,PASSES==3>(Wh, Wl, K, nt0+nt+PD, l15, q, Bh[(nt+PD)%RING], Bl[(nt+PD)%RING]);
    floatx4 acc[4];
#pragma unroll
    for (int m=0; m<4; ++m) acc[m] = (floatx4)0.0f;
#pragma unroll
    for (int ks=0; ks<KS; ++ks){
      const half8 bh = Bh[nt%RING][ks];
#pragma unroll
      for (int m=0; m<4; ++m)
        acc[m] = MFMA16(Ah[m][ks], bh, acc[m]);
      if constexpr (PASSES == 3){
        const half8 bl = Bl[nt%RING][ks];
#pragma unroll
        for (int m=0; m<4; ++m){
          acc[m] = MFMA16(Al[m][ks], bh, acc[m]);
          acc[m] = MFMA16(Ah[m][ks], bl, acc[m]);
        }
      }
    }
    epi(nt0+nt, acc);
  }
}

// ================= Fused kernel: MLPs + Sinkhorn + payments =================
// 256 threads = 4 waves, 64 rows/block (4 m-tiles). N-SPLIT: wave w owns cols
// w*32..w*32+31 of 128-wide layers (n-tiles w*2..w*2+1), cols w*64.. of aL4.
// Per-wave work IDENTICAL to round-7 (584 MFMA, 16 Sinkhorn elements); device
// weight traffic HALVED (one fetch amortized over 64 rows).
// Barrier pattern per hidden stage: read-a | bar | a-stream | read-p | bar |
// p-stream | bar  (a-frags 128 VGPR and p-frags 64 VGPR never co-live).
// LDS: [0,32KB) act_a (64x128 u32 hi|lo), [32,64KB) act_p,
//      [0,64KB) REUSED as aug f32 (64x256) after final-stage pre-reads,
//      [64,68KB) frac f32 (64x16).  69632 B -> 2 blocks/CU = 8 waves/CU.
__global__ __launch_bounds__(256, 2) void fused_kernel(
  const float* __restrict__ X, const _Float16* __restrict__ WT,
  const float* __restrict__ ab0, const float* __restrict__ ab1,
  const float* __restrict__ ab2, const float* __restrict__ ab3,
  const float* __restrict__ pb0, const float* __restrict__ pb1,
  const float* __restrict__ pb2, const float* __restrict__ pb3,
  float* __restrict__ out)
{
  __shared__ unsigned int S[64*256 + 1024];   // 69632 B
  unsigned int* act_a = S;
  unsigned int* act_p = S + 8192;
  float* frac_l = (float*)(S + 16384);
  const int t = threadIdx.x;
  const int w = t >> 6;                      // wave id 0..3
  const int l = t & 63, q = l>>4, l15 = l&15;
  const int nt0 = w*2;                       // n-tile base for 128-wide layers
  const long rb = (long)blockIdx.x * 64;

  // epilogue maker: bias+tanh+pack all 4 m-tiles at global n-tile ntg
  auto epi_act = [&](unsigned int* act, const float* bias, bool lo){
    return [=](int ntg, auto& acc){
      float bb = bias[ntg*16 + l15];
#pragma unroll
      for (int m=0; m<4; ++m){
#pragma unroll
        for (int r=0; r<4; ++r){
          float tv = tanh_f(acc[m][r] + bb);
          act[aaddr(m*16 + q*4 + r, ntg*16 + l15)] = lo ? pack_act(tv) : pack_act_hi(tv);
        }
      }
    };
  };

  // ---- L1 of both nets: X frags for all 4 m-tiles (K=256), own 2 n-tiles ----
  {
    half8 Xf[4][8];
#pragma unroll
    for (int mt=0; mt<4; ++mt){
      float4 xa[8], xb[8];
#pragma unroll
      for (int ks=0; ks<8; ++ks){
        const float* xp = X + (rb + mt*16 + l15)*256 + ks*32 + q*8;
        xa[ks] = *(const float4*)(xp);
        xb[ks] = *(const float4*)(xp + 4);
      }
#pragma unroll
      for (int ks=0; ks<8; ++ks){
        half8 h;
        h[0]=(_Float16)xa[ks].x; h[1]=(_Float16)xa[ks].y; h[2]=(_Float16)xa[ks].z; h[3]=(_Float16)xa[ks].w;
        h[4]=(_Float16)xb[ks].x; h[5]=(_Float16)xb[ks].y; h[6]=(_Float16)xb[ks].z; h[7]=(_Float16)xb[ks].w;
        Xf[mt][ks] = h;
      }
    }
    mfma_stream4<8,1,2,2>(Xf, Xf, WT+O_AW0H, WT+O_AW0H, 256, nt0, l15, q,
                          epi_act(act_a, ab0, true));
    mfma_stream4<8,1,2,2>(Xf, Xf, WT+O_PW0H, WT+O_PW0H, 256, nt0, l15, q,
                          epi_act(act_p, pb0, false));
  }
  __syncthreads();

  // ---- hidden stages: read-a|bar|a-stream|read-p|bar|p-stream|bar ----
#pragma unroll 1
  for (int st=0; st<2; ++st){
    const _Float16* Wah = WT + (st ? O_AW2H : O_AW1H);
    const _Float16* Wal = WT + (st ? O_AW2L : O_AW1L);
    const _Float16* Wph = WT + (st ? O_PW2H : O_PW1H);
    const float* ba = st ? ab2 : ab1;
    const float* bp = st ? pb2 : pb1;
    {
      half8 Fah[4][4], Fal[4][4];
#pragma unroll
      for (int m=0; m<4; ++m)
#pragma unroll
        for (int ks=0; ks<4; ++ks)
          read_frag<true>(act_a, m*16 + l15, ks, q, Fah[m][ks], Fal[m][ks]);
      __syncthreads();
      mfma_stream4<4,3,2,2>(Fah, Fal, Wah, Wal, 128, nt0, l15, q,
                            epi_act(act_a, ba, true));
    }
    {
      half8 Fph[4][4], du;
#pragma unroll
      for (int m=0; m<4; ++m)
#pragma unroll
        for (int ks=0; ks<4; ++ks)
          read_frag<false>(act_p, m*16 + l15, ks, q, Fph[m][ks], du);
      __syncthreads();
      mfma_stream4<4,1,2,3>(Fph, Fph, Wph, Wph, 128, nt0, l15, q,
                            epi_act(act_p, bp, false));
    }
    __syncthreads();
  }

  // ---- final stage: pre-read frags, bar; pL4 (wave0) + aL4 quarter -> aug ----
  {
    half8 Fah[4][4], Fal[4][4], Fph[4][4], du;
#pragma unroll
    for (int m=0; m<4; ++m)
#pragma unroll
      for (int ks=0; ks<4; ++ks)
        read_frag<true>(act_a, m*16 + l15, ks, q, Fah[m][ks], Fal[m][ks]);
    if (w == 0){
#pragma unroll
      for (int m=0; m<4; ++m)
#pragma unroll
        for (int ks=0; ks<4; ++ks)
          read_frag<false>(act_p, m*16 + l15, ks, q, Fph[m][ks], du);
    }
    __syncthreads();
    if (w == 0){
      mfma_stream4<4,1,1,2>(Fph, Fph, WT+O_PW3H, WT+O_PW3H, 128, 0, l15, q,
        [&](int, auto& acc){
          float bb = pb3[l15];
#pragma unroll
          for (int m=0; m<4; ++m)
#pragma unroll
            for (int r=0; r<4; ++r)
              frac_l[(m*16 + q*4 + r)*16 + l15] = sigmoid_f(acc[m][r] + bb);
        });
    }
    // aug quarter: wave w owns cols w*64..w*64+63 (n-tiles 0..3 of its slice);
    // overlays act_a/act_p (all pre-reads done before the barrier above)
    float* augl = (float*)S;
    const int ncol0 = w*64;
    mfma_stream4<4,3,4,2>(Fah, Fal,
                          WT+O_AW3H + ncol0*128, WT+O_AW3L + ncol0*128,
                          128, 0, l15, q,
      [&](int nt, auto& acc){
        float bb = ab3[ncol0 + nt*16 + l15];
#pragma unroll
        for (int m=0; m<4; ++m)
#pragma unroll
          for (int r=0; r<4; ++r)
            augl[(m*16 + q*4 + r)*256 + ncol0 + nt*16 + l15] = acc[m][r] + bb;
      });
    __syncthreads();
  }

  // ================= Sinkhorn + payments: wave w owns elements w*16..w*16+15 ==
  const int c = l & 3;
  const float Ssc = 14.426950408889634f; // (1/EPS)/ln2 : logits in exp2 units
  const float cmask = (c == 3) ? 1.0f : 0.0f;
  const int eL = w*16 + (l >> 2);
  const long e = rb + eL;

  floatx2 Kp[4][8];   // owned columns, rows (2k, 2k+1)
  floatx2 KPp[8];     // pad column 16 (lane 3 only; zero elsewhere), row-pairs

  const float* ap = (const float*)S + eL*256 + 4*c;
#pragma unroll
  for (int k=0;k<8;++k){
    float4 va = *(const float4*)(ap + (2*k  )*16);
    float4 vb = *(const float4*)(ap + (2*k+1)*16);
    Kp[0][k] = (floatx2){va.x*Ssc, vb.x*Ssc};
    Kp[1][k] = (floatx2){va.y*Ssc, vb.y*Ssc};
    Kp[2][k] = (floatx2){va.z*Ssc, vb.z*Ssc};
    Kp[3][k] = (floatx2){va.w*Ssc, vb.w*Ssc};
  }

  // max-subtract + exponentiate (row-wise, across the 4 lanes + pad col 0)
#pragma unroll
  for (int k=0;k<8;++k){
    float m0 = fmaxf(fmaxf(Kp[0][k].x,Kp[1][k].x), fmaxf(Kp[2][k].x,Kp[3][k].x));
    m0 = qmax2(fmaxf(m0, 0.0f));
    float m1 = fmaxf(fmaxf(Kp[0][k].y,Kp[1][k].y), fmaxf(Kp[2][k].y,Kp[3][k].y));
    m1 = qmax2(fmaxf(m1, 0.0f));
    Kp[0][k] = (floatx2){exp2_f(Kp[0][k].x-m0), exp2_f(Kp[0][k].y-m1)};
    Kp[1][k] = (floatx2){exp2_f(Kp[1][k].x-m0), exp2_f(Kp[1][k].y-m1)};
    Kp[2][k] = (floatx2){exp2_f(Kp[2][k].x-m0), exp2_f(Kp[2][k].y-m1)};
    Kp[3][k] = (floatx2){exp2_f(Kp[3][k].x-m0), exp2_f(Kp[3][k].y-m1)};
    KPp[k]   = (floatx2){cmask*exp2_f(-m0), cmask*exp2_f(-m1)};
  }
  // row 16: logits all 0, row max = 0 -> K entries exactly 1 (pad col: cmask)

  float vj0=1.f, vj1=1.f, vj2=1.f, vj3=1.f;
  float v16 = cmask;
  floatx2 u2[8];
  float u16;

  for (int r=0;r<40;++r){
    floatx2 b0=(floatx2){vj0,vj0}, b1=(floatx2){vj1,vj1};
    floatx2 b2=(floatx2){vj2,vj2}, b3=(floatx2){vj3,vj3};
    floatx2 b16=(floatx2){v16,v16};
    // ---- row normalization: u_i = 1 / sum_j K_ij v_j ----
#pragma unroll
    for (int k=0;k<8;++k){
      floatx2 pp = pk_mul2(Kp[0][k], b0);
      pp = pk_fma2(Kp[1][k], b1, pp);
      pp = pk_fma2(Kp[2][k], b2, pp);
      pp = pk_fma2(Kp[3][k], b3, pp);
      pp = pk_fma2(KPp[k], b16, pp);
      float px = qadd2(pp.x);
      float py = qadd2(pp.y);
      u2[k] = (floatx2){rcp_f(px), rcp_f(py)};
    }
    {
      // row 16: K == 1 across real cols, cmask on pad col; a_16 = I = 16
      float p16 = (vj0+vj1) + (vj2+vj3) + cmask*v16;
      p16 = qadd2(p16);
      u16 = 16.0f * rcp_f(p16);
    }
    // ---- column normalization: v_j = 1 / sum_i K_ij u_i ----
    floatx2 t0p = pk_mul2(Kp[0][0], u2[0]);
    floatx2 t1p = pk_mul2(Kp[1][0], u2[0]);
    floatx2 t2p = pk_mul2(Kp[2][0], u2[0]);
    floatx2 t3p = pk_mul2(Kp[3][0], u2[0]);
    floatx2 tPp = pk_mul2(KPp[0],   u2[0]);
#pragma unroll
    for (int k=1;k<8;++k){
      t0p = pk_fma2(Kp[0][k], u2[k], t0p);
      t1p = pk_fma2(Kp[1][k], u2[k], t1p);
      t2p = pk_fma2(Kp[2][k], u2[k], t2p);
      t3p = pk_fma2(Kp[3][k], u2[k], t3p);
      tPp = pk_fma2(KPp[k],   u2[k], tPp);
    }
    float t0 = t0p.x + t0p.y + u16;        // row-16 K == 1
    float t1 = t1p.x + t1p.y + u16;
    float t2 = t2p.x + t2p.y + u16;
    float t3 = t3p.x + t3p.y + u16;
    float t16 = tPp.x + tPp.y + cmask*u16;
    vj0 = rcp_f(t0); vj1 = rcp_f(t1); vj2 = rcp_f(t2); vj3 = rcp_f(t3);
    v16 = cmask * 16.0f * rcp_f(t16 + 1e-30f + (1.0f - cmask));  // b_16 = A = 16; NaN-guard off-lane
  }

  // ---- allocs = u_i K_ij v_j (write) + payments dot fused (reuse w) ----
  float* op = out + e*256 + 4*c;
  const float* bpx = X + e*256 + 4*c;
  float pv0=0.f, pv1=0.f, pv2=0.f, pv3=0.f;
#pragma unroll
  for (int k=0;k<8;++k){
#pragma unroll
    for (int h=0;h<2;++h){
      const int i = 2*k + h;
      const float uu = h ? u2[k].y : u2[k].x;
      const float K0 = h ? Kp[0][k].y : Kp[0][k].x;
      const float K1 = h ? Kp[1][k].y : Kp[1][k].x;
      const float K2 = h ? Kp[2][k].y : Kp[2][k].x;
      const float K3 = h ? Kp[3][k].y : Kp[3][k].x;
      float4 wv;
      wv.x = uu*K0*vj0;
      wv.y = uu*K1*vj1;
      wv.z = uu*K2*vj2;
      wv.w = uu*K3*vj3;
      *(float4*)(op + i*16) = wv;
      float4 bb = *(const float4*)(bpx + i*16);
      float s = wv.x*bb.x + wv.y*bb.y + wv.z*bb.z + wv.w*bb.w;
      s = qadd2(s);
      if ((i>>2) == c){
        const int rr = i & 3;
        if      (rr==0) pv0 = s;
        else if (rr==1) pv1 = s;
        else if (rr==2) pv2 = s;
        else            pv3 = s;
      }
    }
  }
  const float4 fr = *(const float4*)(frac_l + eL*16 + 4*c);
  float4 pvv;
  pvv.x = pv0*fr.x; pvv.y = pv1*fr.y; pvv.z = pv2*fr.z; pvv.w = pv3*fr.w;
  *(float4*)(out + (size_t)NB*256 + e*16 + 4*c) = pvv;
}

// ================= launch =================
extern "C" void kernel_launch(void* const* d_in, const int* in_sizes, int n_in,
                              void* d_out, int out_size, void* d_ws, size_t ws_size,
                              hipStream_t stream)
{
  const float* bids = (const float*)d_in[0];
  const float* aw0 = (const float*)d_in[1];  const float* ab0 = (const float*)d_in[2];
  const float* aw1 = (const float*)d_in[3];  const float* ab1 = (const float*)d_in[4];
  const float* aw2 = (const float*)d_in[5];  const float* ab2 = (const float*)d_in[6];
  const float* aw3 = (const float*)d_in[7];  const float* ab3 = (const float*)d_in[8];
  const float* pw0 = (const float*)d_in[9];  const float* pb0 = (const float*)d_in[10];
  const float* pw1 = (const float*)d_in[11]; const float* pb1 = (const float*)d_in[12];
  const float* pw2 = (const float*)d_in[13]; const float* pb2 = (const float*)d_in[14];
  const float* pw3 = (const float*)d_in[15]; const float* pb3 = (const float*)d_in[16];

  _Float16* WT = (_Float16*)d_ws;

  // nshift = log2(N) where W is K x N (row-major src); dst is N x K (transposed)
  PrepJobs js;
  js.j[0] = { aw0, WT+O_AW0H, nullptr,    7, 32768 };  // 256x128
  js.j[1] = { aw1, WT+O_AW1H, WT+O_AW1L,  7, 16384 };  // 128x128
  js.j[2] = { aw2, WT+O_AW2H, WT+O_AW2L,  7, 16384 };  // 128x128
  js.j[3] = { aw3, WT+O_AW3H, WT+O_AW3L,  8, 32768 };  // 128x256
  js.j[4] = { pw0, WT+O_PW0H, nullptr,    7, 32768 };  // 256x128
  js.j[5] = { pw1, WT+O_PW1H, nullptr,    7, 16384 };  // 128x128
  js.j[6] = { pw2, WT+O_PW2H, nullptr,    7, 16384 };  // 128x128
  js.j[7] = { pw3, WT+O_PW3H, nullptr,    4, 2048  };  // 128x16

  prep_kernel<<<dim3(128,8), 256, 0, stream>>>(js);
  fused_kernel<<<dim3(NB/64), 256, 0, stream>>>(bids, WT, ab0,ab1,ab2,ab3,
                                                pb0,pb1,pb2,pb3, (float*)d_out);
}